// Round 12
// baseline (1769.669 us; speedup 1.0000x reference)
//
#include <hip/hip_runtime.h>
#include <hip/hip_bf16.h>
#include <math.h>

#define NB     128
#define RESX   28
#define DIMC   192
#define NHEADS 6
#define WSZ    7
#define HD     32
#define NTOK   49
#define SCALE  0.17677669529663687f   // 32^-0.5
#define TOK28  (NB*RESX*RESX)         // 100352
#define QSTR   208                    // ushorts per q/k row
#define VSTR   80                     // ushorts per vt row
#define PSTR   80                     // ushorts per P row
#define HSTR   200                    // ushorts per h row (r7-verified)
#define SEPARTS 8

typedef short    bf16x8 __attribute__((ext_vector_type(8)));
typedef float    f32x4  __attribute__((ext_vector_type(4)));

__device__ __forceinline__ float gelu_f(float x){          // exact erf GELU (r7-verified)
    return 0.5f * x * (1.0f + erff(x * 0.70710678118654752f));
}
__device__ __forceinline__ unsigned short f2bf(float f){
    unsigned int u = __float_as_uint(f);
    u += 0x7fffu + ((u >> 16) & 1u);          // RNE
    return (unsigned short)(u >> 16);
}
__device__ __forceinline__ float bf2f(unsigned short u){
    return __uint_as_float(((unsigned int)u) << 16);
}
__device__ __forceinline__ bf16x8 pack8(float4 u, float4 v){
    bf16x8 r;
    r[0]=(short)f2bf(u.x); r[1]=(short)f2bf(u.y); r[2]=(short)f2bf(u.z); r[3]=(short)f2bf(u.w);
    r[4]=(short)f2bf(v.x); r[5]=(short)f2bf(v.y); r[6]=(short)f2bf(v.z); r[7]=(short)f2bf(v.w);
    return r;
}

// ---------------- LayerNorm: one wave per token (4 tokens / 256-thread block)
__global__ __launch_bounds__(256) void ln_kernel(const float* __restrict__ x,
        const float* __restrict__ g, const float* __restrict__ be,
        float* __restrict__ out)
{
    int wid = threadIdx.x >> 6, lane = threadIdx.x & 63;
    size_t tok = (size_t)blockIdx.x * 4 + wid;
    const float* xr = x + tok * DIMC;
    float v0 = xr[lane], v1 = xr[lane + 64], v2 = xr[lane + 128];
    float s  = v0 + v1 + v2;
    float sq = v0*v0 + v1*v1 + v2*v2;
    #pragma unroll
    for (int o = 32; o > 0; o >>= 1){ s += __shfl_xor(s, o); sq += __shfl_xor(sq, o); }
    float mean = s * (1.0f/DIMC);
    float var  = sq * (1.0f/DIMC) - mean*mean;
    float rstd = rsqrtf(var + 1e-5f);
    float* orow = out + tok * DIMC;
    orow[lane]     = (v0-mean)*rstd*g[lane]     + be[lane];
    orow[lane+64]  = (v1-mean)*rstd*g[lane+64]  + be[lane+64];
    orow[lane+128] = (v2-mean)*rstd*g[lane+128] + be[lane+128];
}

// ---------------- depthwise 3x3 (NHWC) + exact GELU
__global__ void dw_gelu_kernel(const float* __restrict__ x, const float* __restrict__ dw,
                               float* __restrict__ y, int H, int W)
{
    int p = blockIdx.x;
    int c = threadIdx.x;
    int w = p % W; int h = (p / W) % H; int b = p / (W*H);
    const float* base = x + (size_t)b*H*W*DIMC;
    float acc = 0.f;
    #pragma unroll
    for (int kh = 0; kh < 3; ++kh){
        int hh = h + kh - 1; if (hh < 0 || hh >= H) continue;
        #pragma unroll
        for (int kw = 0; kw < 3; ++kw){
            int ww = w + kw - 1; if (ww < 0 || ww >= W) continue;
            acc += base[((size_t)hh*W + ww)*DIMC + c] * dw[c*9 + kh*3 + kw];
        }
    }
    y[(size_t)p*DIMC + c] = gelu_f(acc);
}

// ---------------- SE: partial average pool (PARTS blocks per image)
__global__ void se_reduce_kernel(const float* __restrict__ y, float* __restrict__ part,
                                 int HW)
{
    int blk = blockIdx.x;                 // b*SEPARTS + i
    int b = blk / SEPARTS, i = blk - b*SEPARTS;
    int c = threadIdx.x;
    int chunk = (HW + SEPARTS - 1) / SEPARTS;
    int p0 = i*chunk, p1 = p0 + chunk;
    if (p1 > HW) p1 = HW;
    const float* base = y + (size_t)b*HW*DIMC + c;
    float acc = 0.f;
    for (int p = p0; p < p1; ++p) acc += base[(size_t)p*DIMC];
    part[(size_t)blk*DIMC + c] = acc;
}

// ---------------- SE: merge partials -> 192 -> gelu(48) -> sigmoid(192)
__global__ void se_mlp_kernel(const float* __restrict__ part, const float* __restrict__ w1,
                              const float* __restrict__ w2, float* __restrict__ s, int HW)
{
    __shared__ float sl[DIMC];
    __shared__ float mid[48];
    int b = blockIdx.x; int t = threadIdx.x;
    float acc0 = 0.f;
    #pragma unroll
    for (int i = 0; i < SEPARTS; ++i)
        acc0 += part[((size_t)b*SEPARTS + i)*DIMC + t];
    sl[t] = acc0 / (float)HW;
    __syncthreads();
    if (t < 48){
        float acc = 0.f;
        for (int c = 0; c < DIMC; ++c) acc += sl[c] * w1[t*DIMC + c];
        mid[t] = gelu_f(acc);
    }
    __syncthreads();
    float acc = 0.f;
    #pragma unroll 8
    for (int j = 0; j < 48; ++j) acc += mid[j] * w2[t*48 + j];
    s[b*DIMC + t] = 1.0f / (1.0f + expf(-acc));
}

// ---------------- maxpool 3x3 stride 2 pad 1 (NHWC)
__global__ void maxpool_kernel(const float* __restrict__ x, float* __restrict__ out,
                               int H, int W)
{
    int H2 = H >> 1, W2 = W >> 1;
    int p = blockIdx.x;
    int c = threadIdx.x;
    int w2 = p % W2; int h2 = (p / W2) % H2; int b = p / (W2*H2);
    float m = -INFINITY;
    #pragma unroll
    for (int dh = -1; dh <= 1; ++dh){
        int h = 2*h2 + dh; if (h < 0 || h >= H) continue;
        #pragma unroll
        for (int dw = -1; dw <= 1; ++dw){
            int w = 2*w2 + dw; if (w < 0 || w >= W) continue;
            m = fmaxf(m, x[(((size_t)b*H + h)*W + w)*DIMC + c]);
        }
    }
    out[(size_t)p*DIMC + c] = m;
}

// ---------------- merged weight pack: up to 8 segments in one launch
struct PackArgs {
    const float* src[8];
    unsigned short* dst[8];
    int K[8];
    int tEnd[8];
    int nseg;
};
__global__ __launch_bounds__(256) void pack_multi_kernel(PackArgs a)
{
    int t = blockIdx.x*256 + threadIdx.x;
    int seg = 0;
    while (seg < a.nseg && t >= a.tEnd[seg]) ++seg;
    if (seg >= a.nseg) return;
    int t0 = seg ? a.tEnd[seg-1] : 0;
    int tl = t - t0;
    int lane = tl & 63, frag = tl >> 6;
    int K = a.K[seg], ks = K >> 5;
    int j = frag / ks, s = frag - j*ks;
    const float* wr = a.src[seg] + (size_t)(j*16 + (lane & 15))*K + s*32 + ((lane>>4)<<3);
    bf16x8 r = pack8(*(const float4*)wr, *(const float4*)(wr + 4));
    *((bf16x8*)(a.dst[seg] + (size_t)tl*8)) = r;
}

// ---------------- weight-stationary MFMA GEMM (K=192, N=192-chunked in LDS)
__global__ __launch_bounds__(256) void gemmW_kernel(
    const float* __restrict__ in, const unsigned short* __restrict__ Wp,
    const float* __restrict__ bias, const float* __restrict__ res,
    float* __restrict__ out, int N, int M, int ppw,
    const float* __restrict__ sv, int HW)
{
    __shared__ __align__(16) unsigned short wlds[72*512];  // 73728 B
    __shared__ __align__(16) float sbias[192];
    int tid = threadIdx.x;
    int l = tid & 63, w = tid >> 6, c = l & 15, g = l >> 4;
    int nc = blockIdx.y;
    const bf16x8* wsrc = (const bf16x8*)(Wp + (size_t)nc*36864);
    bf16x8* wdst = (bf16x8*)wlds;
    #pragma unroll 2
    for (int i = tid; i < 4608; i += 256) wdst[i] = wsrc[i];
    if (tid < 48){
        float4 bb = bias ? ((const float4*)(bias + nc*192))[tid]
                         : make_float4(0.f,0.f,0.f,0.f);
        ((float4*)sbias)[tid] = bb;
    }
    __syncthreads();
    size_t mbase = (size_t)blockIdx.x*(128*ppw) + (size_t)w*(32*ppw);
    for (int p = 0; p < ppw; ++p){
        size_t m0 = mbase + (size_t)p*32;
        if ((long)m0 >= M) break;
        bool st1 = (long)(m0 + 16) < M;
        const float* ar0 = in + (m0 + c)*DIMC;
        const float* ar1 = ar0 + 16*DIMC;
        bf16x8 b0[6], b1[6];
        #pragma unroll
        for (int s = 0; s < 6; ++s){
            int k0 = s*32 + g*8;
            float4 u0 = *(const float4*)(ar0 + k0), v0 = *(const float4*)(ar0 + k0 + 4);
            float4 u1 = *(const float4*)(ar1 + k0), v1 = *(const float4*)(ar1 + k0 + 4);
            if (sv){
                int bi0 = (int)((m0 + c)/HW), bi1 = (int)((m0 + 16 + c)/HW);
                float4 a0 = *(const float4*)(sv + (size_t)bi0*DIMC + k0);
                float4 a1 = *(const float4*)(sv + (size_t)bi0*DIMC + k0 + 4);
                float4 d0 = *(const float4*)(sv + (size_t)bi1*DIMC + k0);
                float4 d1 = *(const float4*)(sv + (size_t)bi1*DIMC + k0 + 4);
                u0.x*=a0.x; u0.y*=a0.y; u0.z*=a0.z; u0.w*=a0.w;
                v0.x*=a1.x; v0.y*=a1.y; v0.z*=a1.z; v0.w*=a1.w;
                u1.x*=d0.x; u1.y*=d0.y; u1.z*=d0.z; u1.w*=d0.w;
                v1.x*=d1.x; v1.y*=d1.y; v1.z*=d1.z; v1.w*=d1.w;
            }
            b0[s] = pack8(u0, v0);
            b1[s] = pack8(u1, v1);
        }
        #pragma unroll 2
        for (int j = 0; j < 12; ++j){
            float4 bb = *(const float4*)(sbias + j*16 + g*4);
            f32x4 a0 = {bb.x, bb.y, bb.z, bb.w};
            f32x4 a1 = a0;
            const bf16x8* wf = (const bf16x8*)wlds + (size_t)j*6*64 + l;
            #pragma unroll
            for (int s = 0; s < 6; ++s){
                bf16x8 wfr = wf[s*64];
                a0 = __builtin_amdgcn_mfma_f32_16x16x32_bf16(wfr, b0[s], a0, 0, 0, 0);
                a1 = __builtin_amdgcn_mfma_f32_16x16x32_bf16(wfr, b1[s], a1, 0, 0, 0);
            }
            int ncol = nc*192 + j*16 + g*4;
            size_t o0 = (m0 + c)*(size_t)N + ncol;
            size_t o1 = o0 + (size_t)16*N;
            float4 r0 = res ? *(const float4*)(res + o0) : make_float4(0.f,0.f,0.f,0.f);
            *(float4*)(out + o0) = make_float4(a0[0]+r0.x, a0[1]+r0.y, a0[2]+r0.z, a0[3]+r0.w);
            if (st1){
                float4 r1 = res ? *(const float4*)(res + o1) : make_float4(0.f,0.f,0.f,0.f);
                *(float4*)(out + o1) = make_float4(a1[0]+r1.x, a1[1]+r1.y, a1[2]+r1.z, a1[3]+r1.w);
            }
        }
    }
}

// ---------------- fused MFMA MLP v3 (r7 body): wave-split n, T=4 m-tile reuse
// occupancy experiment: 4 waves/EU declared (VGPR cap 128; r7 measured 120)
__global__ __launch_bounds__(256, 4) void mlp_mfma_kernel(
    const float* __restrict__ xln,
    const unsigned short* __restrict__ W1p, const float* __restrict__ b1,
    const unsigned short* __restrict__ W2p, const float* __restrict__ b2,
    float* __restrict__ xout)
{
    __shared__ __align__(16) unsigned short h[64*HSTR];   // 25600 B
    int l = threadIdx.x & 63, w = threadIdx.x >> 6;
    int c = l & 15, g = l >> 4;
    size_t m0 = (size_t)blockIdx.x*64;
    bf16x8 bx[4][6];
    #pragma unroll
    for (int mt = 0; mt < 4; ++mt){
        const float* ar = xln + (m0 + mt*16 + c)*DIMC;
        #pragma unroll
        for (int s = 0; s < 6; ++s){
            int k0 = s*32 + g*8;
            bx[mt][s] = pack8(*(const float4*)(ar + k0), *(const float4*)(ar + k0 + 4));
        }
    }
    f32x4 acc[4][3];
    #pragma unroll
    for (int jj = 0; jj < 3; ++jj){
        float4 b4 = *(const float4*)(b2 + (3*w + jj)*16 + g*4);
        f32x4 v = {b4.x, b4.y, b4.z, b4.w};
        #pragma unroll
        for (int mt = 0; mt < 4; ++mt) acc[mt][jj] = v;
    }
    for (int ch = 0; ch < 4; ++ch){
        #pragma unroll
        for (int jj = 0; jj < 3; ++jj){
            int j = ch*12 + 3*w + jj;
            float4 b40 = *(const float4*)(b1 + j*16 + g*4);
            f32x4 a0 = {b40.x, b40.y, b40.z, b40.w};
            f32x4 a1 = a0, a2 = a0, a3 = a0;
            const bf16x8* wp = (const bf16x8*)(W1p + ((size_t)(j*6)*64 + l)*8);
            #pragma unroll
            for (int s = 0; s < 6; ++s){
                bf16x8 wfr = wp[s*64];
                a0 = __builtin_amdgcn_mfma_f32_16x16x32_bf16(wfr, bx[0][s], a0, 0, 0, 0);
                a1 = __builtin_amdgcn_mfma_f32_16x16x32_bf16(wfr, bx[1][s], a1, 0, 0, 0);
                a2 = __builtin_amdgcn_mfma_f32_16x16x32_bf16(wfr, bx[2][s], a2, 0, 0, 0);
                a3 = __builtin_amdgcn_mfma_f32_16x16x32_bf16(wfr, bx[3][s], a3, 0, 0, 0);
            }
            int fb = (3*w + jj)*16 + g*4;
            ushort4 u;
            u.x=f2bf(gelu_f(a0[0])); u.y=f2bf(gelu_f(a0[1]));
            u.z=f2bf(gelu_f(a0[2])); u.w=f2bf(gelu_f(a0[3]));
            *(ushort4*)(h + (0*16 + c)*HSTR + fb) = u;
            u.x=f2bf(gelu_f(a1[0])); u.y=f2bf(gelu_f(a1[1]));
            u.z=f2bf(gelu_f(a1[2])); u.w=f2bf(gelu_f(a1[3]));
            *(ushort4*)(h + (1*16 + c)*HSTR + fb) = u;
            u.x=f2bf(gelu_f(a2[0])); u.y=f2bf(gelu_f(a2[1]));
            u.z=f2bf(gelu_f(a2[2])); u.w=f2bf(gelu_f(a2[3]));
            *(ushort4*)(h + (2*16 + c)*HSTR + fb) = u;
            u.x=f2bf(gelu_f(a3[0])); u.y=f2bf(gelu_f(a3[1]));
            u.z=f2bf(gelu_f(a3[2])); u.w=f2bf(gelu_f(a3[3]));
            *(ushort4*)(h + (3*16 + c)*HSTR + fb) = u;
        }
        __syncthreads();
        #pragma unroll
        for (int s = 0; s < 6; ++s){
            bf16x8 hf[4];
            #pragma unroll
            for (int mt = 0; mt < 4; ++mt)
                hf[mt] = *(const bf16x8*)(h + (mt*16 + c)*HSTR + s*32 + g*8);
            #pragma unroll
            for (int jj = 0; jj < 3; ++jj){
                int j = 3*w + jj;
                bf16x8 wf = *(const bf16x8*)(W2p + ((size_t)(j*24 + ch*6 + s)*64 + l)*8);
                #pragma unroll
                for (int mt = 0; mt < 4; ++mt)
                    acc[mt][jj] = __builtin_amdgcn_mfma_f32_16x16x32_bf16(wf, hf[mt], acc[mt][jj], 0, 0, 0);
            }
        }
        __syncthreads();
    }
    #pragma unroll
    for (int mt = 0; mt < 4; ++mt){
        #pragma unroll
        for (int jj = 0; jj < 3; ++jj){
            size_t o = (m0 + mt*16 + c)*DIMC + (3*w + jj)*16 + g*4;
            float4 r = *(const float4*)(xout + o);
            *(float4*)(xout + o) = make_float4(acc[mt][jj][0]+r.x, acc[mt][jj][1]+r.y,
                                               acc[mt][jj][2]+r.z, acc[mt][jj][3]+r.w);
        }
    }
}

// ---------------- fused qkv + window attention, all-MFMA (r7-verified)
__global__ __launch_bounds__(512, 2) void attn_fused_kernel(
    float* __restrict__ xio, const unsigned short* __restrict__ Wp,
    const float* __restrict__ bias, const float* __restrict__ qg,
    const float* __restrict__ rpb, int F)
{
    __shared__ __align__(16) unsigned short q_lds[64*QSTR];  // 26624 B
    __shared__ __align__(16) unsigned short k_lds[64*QSTR];  // 26624 B
    __shared__ __align__(16) unsigned short vt[192*VSTR];    // 30720 B
    __shared__ __align__(16) unsigned short pp[8*16*PSTR];   // 20480 B
    __shared__ float sinv_l[8*16];
    __shared__ float rpb_l[NHEADS*169];
    int tid = threadIdx.x;
    int w8 = tid >> 6;
    int l = tid & 63, c = l & 15, g = l >> 4;
    int blk = blockIdx.x;
    int b = blk >> 4, win = blk & 15;
    int wr = win >> 2, wc = win & 3;
    bool isglobal = (F == 384);

    for (int i = tid; i < 15*QSTR; i += 512){
        q_lds[49*QSTR + i] = 0; k_lds[49*QSTR + i] = 0;
    }
    for (int i = tid; i < 192*15; i += 512){
        int d = i / 15, t = 49 + (i - d*15);
        vt[d*VSTR + t] = 0;
    }
    for (int i = tid; i < NHEADS*169; i += 512){
        int hd = i / 169, r = i - hd*169;
        rpb_l[i] = rpb[r*NHEADS + hd];
    }

    // ---- phase 1: qkv projection via MFMA
    {
        bf16x8 bx[4][6];
        #pragma unroll
        for (int mt = 0; mt < 4; ++mt){
            int t = mt*16 + c;
            if (t < NTOK){
                int hh = wr*WSZ + t/WSZ, ww = wc*WSZ + t - (t/WSZ)*WSZ;
                const float* ar = xio + (((size_t)b*RESX + hh)*RESX + ww)*DIMC;
                #pragma unroll
                for (int s = 0; s < 6; ++s){
                    int k0 = s*32 + g*8;
                    bx[mt][s] = pack8(*(const float4*)(ar + k0), *(const float4*)(ar + k0 + 4));
                }
            } else {
                bf16x8 z = {0,0,0,0,0,0,0,0};
                #pragma unroll
                for (int s = 0; s < 6; ++s) bx[mt][s] = z;
            }
        }
        int ntile = F >> 4;    // 36 local / 24 global
        for (int jn = w8; jn < ntile; jn += 8){
            float4 bb4 = *(const float4*)(bias + jn*16 + g*4);
            f32x4 a0 = {bb4.x, bb4.y, bb4.z, bb4.w};
            f32x4 a1 = a0, a2 = a0, a3 = a0;
            const bf16x8* wp = (const bf16x8*)(Wp + ((size_t)(jn*6)*64 + l)*8);
            #pragma unroll
            for (int s = 0; s < 6; ++s){
                bf16x8 wfr = wp[s*64];
                a0 = __builtin_amdgcn_mfma_f32_16x16x32_bf16(wfr, bx[0][s], a0, 0, 0, 0);
                a1 = __builtin_amdgcn_mfma_f32_16x16x32_bf16(wfr, bx[1][s], a1, 0, 0, 0);
                a2 = __builtin_amdgcn_mfma_f32_16x16x32_bf16(wfr, bx[2][s], a2, 0, 0, 0);
                a3 = __builtin_amdgcn_mfma_f32_16x16x32_bf16(wfr, bx[3][s], a3, 0, 0, 0);
            }
            int sect = jn / 12 + (isglobal ? 1 : 0);   // 0=q,1=k,2=v
            int frel = (jn - (jn/12)*12)*16 + g*4;
            f32x4 av[4] = {a0, a1, a2, a3};
            #pragma unroll
            for (int mt = 0; mt < 4; ++mt){
                int t = mt*16 + c;
                if (t >= NTOK) continue;
                f32x4 a = av[mt];
                if (sect == 0){
                    ushort4 u;
                    u.x=f2bf(a[0]*SCALE); u.y=f2bf(a[1]*SCALE);
                    u.z=f2bf(a[2]*SCALE); u.w=f2bf(a[3]*SCALE);
                    *(ushort4*)(q_lds + t*QSTR + frel) = u;
                } else if (sect == 1){
                    ushort4 u;
                    u.x=f2bf(a[0]); u.y=f2bf(a[1]); u.z=f2bf(a[2]); u.w=f2bf(a[3]);
                    *(ushort4*)(k_lds + t*QSTR + frel) = u;
                } else {
                    vt[(frel+0)*VSTR + t] = f2bf(a[0]);
                    vt[(frel+1)*VSTR + t] = f2bf(a[1]);
                    vt[(frel+2)*VSTR + t] = f2bf(a[2]);
                    vt[(frel+3)*VSTR + t] = f2bf(a[3]);
                }
            }
        }
        if (isglobal){
            for (int i = tid; i < NTOK*48; i += 512){
                int t = i / 48, f4 = i - (i/48)*48;
                float4 qv = *(const float4*)(qg + ((size_t)b*NTOK + t)*DIMC + f4*4);
                ushort4 u;
                u.x=f2bf(qv.x*SCALE); u.y=f2bf(qv.y*SCALE);
                u.z=f2bf(qv.z*SCALE); u.w=f2bf(qv.w*SCALE);
                *(ushort4*)(q_lds + t*QSTR + f4*4) = u;
            }
        }
    }
    __syncthreads();

    // ---- 24 attention units, 3 per wave (pp/sinv rows wave-private: no barriers)
    for (int uu = 0; uu < 3; ++uu){
        int unit = w8*3 + uu;
        int ti = unit / 6, hd = unit - (unit/6)*6;
        bf16x8 qa = *(const bf16x8*)(q_lds + (16*ti + c)*QSTR + hd*HD + g*8);
        f32x4 S[4];
        {
            const f32x4 z = {0.f, 0.f, 0.f, 0.f};
            #pragma unroll
            for (int tj = 0; tj < 4; ++tj){
                bf16x8 kb = *(const bf16x8*)(k_lds + (16*tj + c)*QSTR + hd*HD + g*8);
                S[tj] = __builtin_amdgcn_mfma_f32_16x16x32_bf16(qa, kb, z, 0, 0, 0);
            }
        }
        float tot[4] = {0.f, 0.f, 0.f, 0.f};
        unsigned short pu[4][4];
        int ibase = 16*ti + g*4;
        #pragma unroll
        for (int tj = 0; tj < 4; ++tj){
            int j = 16*tj + c;
            bool jok = (j < NTOK);
            int jc = jok ? j : 0;
            int rj = jc / 7, cj = jc - rj*7;
            #pragma unroll
            for (int r = 0; r < 4; ++r){
                int i = ibase + r;
                int ic = (i < NTOK) ? i : 0;
                int ri = ic / 7, ci = ic - ri*7;
                unsigned short u16 = 0;
                if (jok){
                    float bv = rpb_l[hd*169 + (ri - rj + 6)*13 + (ci - cj + 6)];
                    u16 = f2bf(__expf(S[tj][r] + bv));
                }
                pu[tj][r] = u16;
                tot[r] += bf2f(u16);
            }
        }
        #pragma unroll
        for (int r = 0; r < 4; ++r){
            float t0 = tot[r];
            t0 += __shfl_xor(t0, 1); t0 += __shfl_xor(t0, 2);
            t0 += __shfl_xor(t0, 4); t0 += __shfl_xor(t0, 8);
            tot[r] = t0;
        }
        if (c == 0){
            #pragma unroll
            for (int r = 0; r < 4; ++r)
                sinv_l[w8*16 + g*4 + r] = 1.0f / tot[r];
        }
        #pragma unroll
        for (int tj = 0; tj < 4; ++tj){
            #pragma unroll
            for (int r = 0; r < 4; ++r)
                pp[(w8*16 + g*4 + r)*PSTR + 16*tj + c] = pu[tj][r];
        }
        bf16x8 pb0 = *(const bf16x8*)(pp + (w8*16 + c)*PSTR + g*8);
        bf16x8 pb1 = *(const bf16x8*)(pp + (w8*16 + c)*PSTR + 32 + g*8);
        float si = sinv_l[w8*16 + c];
        int t = 16*ti + c;
        #pragma unroll
        for (int dm = 0; dm < 2; ++dm){
            int vrow = hd*HD + dm*16 + c;
            bf16x8 va0 = *(const bf16x8*)(vt + vrow*VSTR + g*8);
            bf16x8 va1 = *(const bf16x8*)(vt + vrow*VSTR + 32 + g*8);
            const f32x4 z = {0.f, 0.f, 0.f, 0.f};
            f32x4 o = __builtin_amdgcn_mfma_f32_16x16x32_bf16(va0, pb0, z, 0, 0, 0);
            o = __builtin_amdgcn_mfma_f32_16x16x32_bf16(va1, pb1, o, 0, 0, 0);
            if (t < NTOK){
                int hh = wr*WSZ + t/WSZ, ww = wc*WSZ + t - (t/WSZ)*WSZ;
                float4 ov = make_float4(o[0]*si, o[1]*si, o[2]*si, o[3]*si);
                *(float4*)(xio + (((size_t)b*RESX + hh)*RESX + ww)*DIMC
                           + hd*HD + dm*16 + g*4) = ov;
            }
        }
    }
}

static inline int pick_ppw(int M){
    int ppw = M / 65536;                 // target >= ~512 blocks (2 per CU)
    if (ppw < 1) ppw = 1;
    if (ppw > 8) ppw = 8;
    return ppw;
}

extern "C" void kernel_launch(void* const* d_in, const int* in_sizes, int n_in,
                              void* d_out, int out_size, void* d_ws, size_t ws_size,
                              hipStream_t stream)
{
    (void)in_sizes; (void)n_in; (void)out_size;
    const float* x = (const float*)d_in[0];
    const float* fe_dw[2]  = {(const float*)d_in[1], (const float*)d_in[5]};
    const float* fe_se1[2] = {(const float*)d_in[2], (const float*)d_in[6]};
    const float* fe_se2[2] = {(const float*)d_in[3], (const float*)d_in[7]};
    const float* fe_pw[2]  = {(const float*)d_in[4], (const float*)d_in[8]};
    const float* n1g[2]  = {(const float*)d_in[9],  (const float*)d_in[22]};
    const float* n1b[2]  = {(const float*)d_in[10], (const float*)d_in[23]};
    const float* qkvw[2] = {(const float*)d_in[11], (const float*)d_in[24]};
    const float* qkvb[2] = {(const float*)d_in[12], (const float*)d_in[25]};
    const float* rpb[2]  = {(const float*)d_in[13], (const float*)d_in[26]};
    const float* prjw[2] = {(const float*)d_in[14], (const float*)d_in[27]};
    const float* prjb[2] = {(const float*)d_in[15], (const float*)d_in[28]};
    const float* n2g[2]  = {(const float*)d_in[16], (const float*)d_in[29]};
    const float* n2b[2]  = {(const float*)d_in[17], (const float*)d_in[30]};
    const float* fc1w[2] = {(const float*)d_in[18], (const float*)d_in[31]};
    const float* fc1b[2] = {(const float*)d_in[19], (const float*)d_in[32]};
    const float* fc2w[2] = {(const float*)d_in[20], (const float*)d_in[33]};
    const float* fc2b[2] = {(const float*)d_in[21], (const float*)d_in[34]};

    float* out = (float*)d_out;
    float* ws = (float*)d_ws;
    const size_t n28 = (size_t)NB*RESX*RESX*DIMC;     // 19,267,584
    const size_t n14 = (size_t)NB*14*14*DIMC;         //  4,816,896
    const size_t n7  = (size_t)NB*7*7*DIMC;           //  1,204,224
    float* region0 = ws;
    float* x7      = region0 + n28;      // also SE-partials scratch during phase A
    float* s0      = x7 + n7;
    float* s1      = s0 + NB*DIMC;
    float* pwpk_f  = s1 + NB*DIMC;       // 2 packed pw weights
    float* dyn     = pwpk_f + 36864;     // phase A: x14 ; phase B: packed weights
    size_t fixedf  = n28 + n7 + 2ull*NB*DIMC + 36864;
    if (ws_size < (fixedf + n14) * sizeof(float)) return;
    float* x14 = dyn;
    unsigned short* pwpk = (unsigned short*)pwpk_f;

    unsigned short* pk = (unsigned short*)dyn;
    const size_t PK_QKV0 = 0;                 // 576x192
    const size_t PK_QKV1 = PK_QKV0 + 576*192; // 384x192
    const size_t PK_PRJ0 = PK_QKV1 + 384*192;
    const size_t PK_PRJ1 = PK_PRJ0 + 192*192;
    const size_t PK_FC10 = PK_PRJ1 + 192*192;
    const size_t PK_FC11 = PK_FC10 + 768*192;
    const size_t PK_FC20 = PK_FC11 + 768*192;
    const size_t PK_FC21 = PK_FC20 + 192*768; // total 847872 ushorts < n14 floats

    // ---- pack pw weights (2 segments, one launch)
    {
        PackArgs a = {};
        a.src[0] = fe_pw[0]; a.dst[0] = pwpk;         a.K[0] = 192; a.tEnd[0] = 4608;
        a.src[1] = fe_pw[1]; a.dst[1] = pwpk + 36864; a.K[1] = 192; a.tEnd[1] = 9216;
        a.nseg = 2;
        pack_multi_kernel<<<(9216 + 255)/256, 256, 0, stream>>>(a);
    }

    // ---- Phase A: GlobalQueryGen: 28 -> 14 -> 7
    for (int fe = 0; fe < 2; ++fe){
        int H = fe ? 14 : 28;
        int HW = H * H;
        int M = NB * HW;
        const float* src = fe ? x14 : x;
        float* dst = fe ? x7 : x14;
        dw_gelu_kernel<<<NB*HW, DIMC, 0, stream>>>(src, fe_dw[fe], region0, H, H);
        se_reduce_kernel<<<NB*SEPARTS, DIMC, 0, stream>>>(region0, x7, HW);
        se_mlp_kernel<<<NB, DIMC, 0, stream>>>(x7, fe_se1[fe], fe_se2[fe], s1, HW);
        int ppw = pick_ppw(M);
        dim3 ga((M + 128*ppw - 1) / (128*ppw), 1);
        gemmW_kernel<<<ga, 256, 0, stream>>>(region0, pwpk + fe*36864, nullptr,
                                             src, region0, DIMC, M, ppw, s1, HW);
        maxpool_kernel<<<NB*(H/2)*(H/2), DIMC, 0, stream>>>(region0, dst, H, H);
    }

    // ---- pack remaining weights (8 segments, one launch; x14 dead now)
    {
        PackArgs a = {};
        const float* srcs[8] = {qkvw[0], qkvw[1], prjw[0], prjw[1],
                                fc1w[0], fc1w[1], fc2w[0], fc2w[1]};
        size_t offs[8] = {PK_QKV0, PK_QKV1, PK_PRJ0, PK_PRJ1,
                          PK_FC10, PK_FC11, PK_FC20, PK_FC21};
        int kk[8]  = {192, 192, 192, 192, 192, 192, 768, 768};
        int cnt[8] = {13824, 9216, 4608, 4608, 18432, 18432, 18432, 18432};
        int cum = 0;
        for (int i = 0; i < 8; ++i){
            a.src[i] = srcs[i]; a.dst[i] = pk + offs[i]; a.K[i] = kk[i];
            cum += cnt[i]; a.tEnd[i] = cum;
        }
        a.nseg = 8;
        pack_multi_kernel<<<(cum + 255)/256, 256, 0, stream>>>(a);
    }

    // ---- Phase B: two attention blocks (0=local, 1=global query)
    for (int blk = 0; blk < 2; ++blk){
        const float* xin = blk ? (const float*)out : x;
        ln_kernel<<<TOK28/4, 256, 0, stream>>>(xin, n1g[blk], n1b[blk], region0);
        int F = blk ? 384 : 576;
        attn_fused_kernel<<<NB*16, 512, 0, stream>>>(
            region0, pk + (blk ? PK_QKV1 : PK_QKV0), qkvb[blk],
            blk ? x7 : nullptr, rpb[blk], F);
        {
            int M = TOK28;
            int ppw = pick_ppw(M);
            dim3 gp((M + 128*ppw - 1) / (128*ppw), 1);
            gemmW_kernel<<<gp, 256, 0, stream>>>(region0,
                pk + (blk ? PK_PRJ1 : PK_PRJ0), prjb[blk], xin, out,
                DIMC, M, ppw, nullptr, 0);
        }
        ln_kernel<<<TOK28/4, 256, 0, stream>>>(out, n2g[blk], n2b[blk], region0);
        mlp_mfma_kernel<<<TOK28/64, 256, 0, stream>>>(region0,
            pk + (blk ? PK_FC11 : PK_FC10), fc1b[blk],
            pk + (blk ? PK_FC21 : PK_FC20), fc2b[blk], out);
    }
}

// Round 13
// 1266.190 us; speedup vs baseline: 1.3976x; 1.3976x over previous
//
#include <hip/hip_runtime.h>
#include <hip/hip_bf16.h>
#include <math.h>

#define NB     128
#define RESX   28
#define DIMC   192
#define NHEADS 6
#define WSZ    7
#define HD     32
#define NTOK   49
#define SCALE  0.17677669529663687f   // 32^-0.5
#define TOK28  (NB*RESX*RESX)         // 100352
#define QSTR   208                    // ushorts per q/k row
#define VSTR   80                     // ushorts per vt row
#define PSTR   80                     // ushorts per P row
#define HSTR   200                    // ushorts per h row (r7-verified)
#define SEPARTS 8

typedef short    bf16x8 __attribute__((ext_vector_type(8)));
typedef float    f32x4  __attribute__((ext_vector_type(4)));

__device__ __forceinline__ float gelu_f(float x){          // exact erf GELU (r7-verified)
    return 0.5f * x * (1.0f + erff(x * 0.70710678118654752f));
}
__device__ __forceinline__ unsigned short f2bf(float f){
    unsigned int u = __float_as_uint(f);
    u += 0x7fffu + ((u >> 16) & 1u);          // RNE
    return (unsigned short)(u >> 16);
}
__device__ __forceinline__ float bf2f(unsigned short u){
    return __uint_as_float(((unsigned int)u) << 16);
}
__device__ __forceinline__ bf16x8 pack8(float4 u, float4 v){
    bf16x8 r;
    r[0]=(short)f2bf(u.x); r[1]=(short)f2bf(u.y); r[2]=(short)f2bf(u.z); r[3]=(short)f2bf(u.w);
    r[4]=(short)f2bf(v.x); r[5]=(short)f2bf(v.y); r[6]=(short)f2bf(v.z); r[7]=(short)f2bf(v.w);
    return r;
}

// ---------------- LayerNorm: one wave per token (4 tokens / 256-thread block)
__global__ __launch_bounds__(256) void ln_kernel(const float* __restrict__ x,
        const float* __restrict__ g, const float* __restrict__ be,
        float* __restrict__ out)
{
    int wid = threadIdx.x >> 6, lane = threadIdx.x & 63;
    size_t tok = (size_t)blockIdx.x * 4 + wid;
    const float* xr = x + tok * DIMC;
    float v0 = xr[lane], v1 = xr[lane + 64], v2 = xr[lane + 128];
    float s  = v0 + v1 + v2;
    float sq = v0*v0 + v1*v1 + v2*v2;
    #pragma unroll
    for (int o = 32; o > 0; o >>= 1){ s += __shfl_xor(s, o); sq += __shfl_xor(sq, o); }
    float mean = s * (1.0f/DIMC);
    float var  = sq * (1.0f/DIMC) - mean*mean;
    float rstd = rsqrtf(var + 1e-5f);
    float* orow = out + tok * DIMC;
    orow[lane]     = (v0-mean)*rstd*g[lane]     + be[lane];
    orow[lane+64]  = (v1-mean)*rstd*g[lane+64]  + be[lane+64];
    orow[lane+128] = (v2-mean)*rstd*g[lane+128] + be[lane+128];
}

// ---------------- depthwise 3x3 (NHWC) + exact GELU
__global__ void dw_gelu_kernel(const float* __restrict__ x, const float* __restrict__ dw,
                               float* __restrict__ y, int H, int W)
{
    int p = blockIdx.x;
    int c = threadIdx.x;
    int w = p % W; int h = (p / W) % H; int b = p / (W*H);
    const float* base = x + (size_t)b*H*W*DIMC;
    float acc = 0.f;
    #pragma unroll
    for (int kh = 0; kh < 3; ++kh){
        int hh = h + kh - 1; if (hh < 0 || hh >= H) continue;
        #pragma unroll
        for (int kw = 0; kw < 3; ++kw){
            int ww = w + kw - 1; if (ww < 0 || ww >= W) continue;
            acc += base[((size_t)hh*W + ww)*DIMC + c] * dw[c*9 + kh*3 + kw];
        }
    }
    y[(size_t)p*DIMC + c] = gelu_f(acc);
}

// ---------------- SE: partial average pool (SEPARTS blocks per image)
__global__ void se_reduce_kernel(const float* __restrict__ y, float* __restrict__ part,
                                 int HW)
{
    int blk = blockIdx.x;                 // b*SEPARTS + i
    int b = blk / SEPARTS, i = blk - b*SEPARTS;
    int c = threadIdx.x;
    int chunk = (HW + SEPARTS - 1) / SEPARTS;
    int p0 = i*chunk, p1 = p0 + chunk;
    if (p1 > HW) p1 = HW;
    const float* base = y + (size_t)b*HW*DIMC + c;
    float acc = 0.f;
    for (int p = p0; p < p1; ++p) acc += base[(size_t)p*DIMC];
    part[(size_t)blk*DIMC + c] = acc;
}

// ---------------- SE: merge partials -> 192 -> gelu(48) -> sigmoid(192)
__global__ void se_mlp_kernel(const float* __restrict__ part, const float* __restrict__ w1,
                              const float* __restrict__ w2, float* __restrict__ s, int HW)
{
    __shared__ float sl[DIMC];
    __shared__ float mid[48];
    int b = blockIdx.x; int t = threadIdx.x;
    float acc0 = 0.f;
    #pragma unroll
    for (int i = 0; i < SEPARTS; ++i)
        acc0 += part[((size_t)b*SEPARTS + i)*DIMC + t];
    sl[t] = acc0 / (float)HW;
    __syncthreads();
    if (t < 48){
        float acc = 0.f;
        for (int c = 0; c < DIMC; ++c) acc += sl[c] * w1[t*DIMC + c];
        mid[t] = gelu_f(acc);
    }
    __syncthreads();
    float acc = 0.f;
    #pragma unroll 8
    for (int j = 0; j < 48; ++j) acc += mid[j] * w2[t*48 + j];
    s[b*DIMC + t] = 1.0f / (1.0f + expf(-acc));
}

// ---------------- maxpool 3x3 stride 2 pad 1 (NHWC)
__global__ void maxpool_kernel(const float* __restrict__ x, float* __restrict__ out,
                               int H, int W)
{
    int H2 = H >> 1, W2 = W >> 1;
    int p = blockIdx.x;
    int c = threadIdx.x;
    int w2 = p % W2; int h2 = (p / W2) % H2; int b = p / (W2*H2);
    float m = -INFINITY;
    #pragma unroll
    for (int dh = -1; dh <= 1; ++dh){
        int h = 2*h2 + dh; if (h < 0 || h >= H) continue;
        #pragma unroll
        for (int dw = -1; dw <= 1; ++dw){
            int w = 2*w2 + dw; if (w < 0 || w >= W) continue;
            m = fmaxf(m, x[(((size_t)b*H + h)*W + w)*DIMC + c]);
        }
    }
    out[(size_t)p*DIMC + c] = m;
}

// ---------------- merged weight pack: up to 8 segments in one launch
struct PackArgs {
    const float* src[8];
    unsigned short* dst[8];
    int K[8];
    int tEnd[8];
    int nseg;
};
__global__ __launch_bounds__(256) void pack_multi_kernel(PackArgs a)
{
    int t = blockIdx.x*256 + threadIdx.x;
    int seg = 0;
    while (seg < a.nseg && t >= a.tEnd[seg]) ++seg;
    if (seg >= a.nseg) return;
    int t0 = seg ? a.tEnd[seg-1] : 0;
    int tl = t - t0;
    int lane = tl & 63, frag = tl >> 6;
    int K = a.K[seg], ks = K >> 5;
    int j = frag / ks, s = frag - j*ks;
    const float* wr = a.src[seg] + (size_t)(j*16 + (lane & 15))*K + s*32 + ((lane>>4)<<3);
    bf16x8 r = pack8(*(const float4*)wr, *(const float4*)(wr + 4));
    *((bf16x8*)(a.dst[seg] + (size_t)tl*8)) = r;
}

// ---------------- weight-stationary MFMA GEMM (K=192, N=192-chunked in LDS)
__global__ __launch_bounds__(256) void gemmW_kernel(
    const float* __restrict__ in, const unsigned short* __restrict__ Wp,
    const float* __restrict__ bias, const float* __restrict__ res,
    float* __restrict__ out, int N, int M, int ppw,
    const float* __restrict__ sv, int HW)
{
    __shared__ __align__(16) unsigned short wlds[72*512];  // 73728 B
    __shared__ __align__(16) float sbias[192];
    int tid = threadIdx.x;
    int l = tid & 63, w = tid >> 6, c = l & 15, g = l >> 4;
    int nc = blockIdx.y;
    const bf16x8* wsrc = (const bf16x8*)(Wp + (size_t)nc*36864);
    bf16x8* wdst = (bf16x8*)wlds;
    #pragma unroll 2
    for (int i = tid; i < 4608; i += 256) wdst[i] = wsrc[i];
    if (tid < 48){
        float4 bb = bias ? ((const float4*)(bias + nc*192))[tid]
                         : make_float4(0.f,0.f,0.f,0.f);
        ((float4*)sbias)[tid] = bb;
    }
    __syncthreads();
    size_t mbase = (size_t)blockIdx.x*(128*ppw) + (size_t)w*(32*ppw);
    for (int p = 0; p < ppw; ++p){
        size_t m0 = mbase + (size_t)p*32;
        if ((long)m0 >= M) break;
        bool st1 = (long)(m0 + 16) < M;
        const float* ar0 = in + (m0 + c)*DIMC;
        const float* ar1 = ar0 + 16*DIMC;
        bf16x8 b0[6], b1[6];
        #pragma unroll
        for (int s = 0; s < 6; ++s){
            int k0 = s*32 + g*8;
            float4 u0 = *(const float4*)(ar0 + k0), v0 = *(const float4*)(ar0 + k0 + 4);
            float4 u1 = *(const float4*)(ar1 + k0), v1 = *(const float4*)(ar1 + k0 + 4);
            if (sv){
                int bi0 = (int)((m0 + c)/HW), bi1 = (int)((m0 + 16 + c)/HW);
                float4 a0 = *(const float4*)(sv + (size_t)bi0*DIMC + k0);
                float4 a1 = *(const float4*)(sv + (size_t)bi0*DIMC + k0 + 4);
                float4 d0 = *(const float4*)(sv + (size_t)bi1*DIMC + k0);
                float4 d1 = *(const float4*)(sv + (size_t)bi1*DIMC + k0 + 4);
                u0.x*=a0.x; u0.y*=a0.y; u0.z*=a0.z; u0.w*=a0.w;
                v0.x*=a1.x; v0.y*=a1.y; v0.z*=a1.z; v0.w*=a1.w;
                u1.x*=d0.x; u1.y*=d0.y; u1.z*=d0.z; u1.w*=d0.w;
                v1.x*=d1.x; v1.y*=d1.y; v1.z*=d1.z; v1.w*=d1.w;
            }
            b0[s] = pack8(u0, v0);
            b1[s] = pack8(u1, v1);
        }
        #pragma unroll 2
        for (int j = 0; j < 12; ++j){
            float4 bb = *(const float4*)(sbias + j*16 + g*4);
            f32x4 a0 = {bb.x, bb.y, bb.z, bb.w};
            f32x4 a1 = a0;
            const bf16x8* wf = (const bf16x8*)wlds + (size_t)j*6*64 + l;
            #pragma unroll
            for (int s = 0; s < 6; ++s){
                bf16x8 wfr = wf[s*64];
                a0 = __builtin_amdgcn_mfma_f32_16x16x32_bf16(wfr, b0[s], a0, 0, 0, 0);
                a1 = __builtin_amdgcn_mfma_f32_16x16x32_bf16(wfr, b1[s], a1, 0, 0, 0);
            }
            int ncol = nc*192 + j*16 + g*4;
            size_t o0 = (m0 + c)*(size_t)N + ncol;
            size_t o1 = o0 + (size_t)16*N;
            float4 r0 = res ? *(const float4*)(res + o0) : make_float4(0.f,0.f,0.f,0.f);
            *(float4*)(out + o0) = make_float4(a0[0]+r0.x, a0[1]+r0.y, a0[2]+r0.z, a0[3]+r0.w);
            if (st1){
                float4 r1 = res ? *(const float4*)(res + o1) : make_float4(0.f,0.f,0.f,0.f);
                *(float4*)(out + o1) = make_float4(a1[0]+r1.x, a1[1]+r1.y, a1[2]+r1.z, a1[3]+r1.w);
            }
        }
    }
}

// ---------------- fused MFMA MLP v3 (r7-verified config: 256 threads, 2 waves/EU)
__global__ __launch_bounds__(256, 2) void mlp_mfma_kernel(
    const float* __restrict__ xln,
    const unsigned short* __restrict__ W1p, const float* __restrict__ b1,
    const unsigned short* __restrict__ W2p, const float* __restrict__ b2,
    float* __restrict__ xout)
{
    __shared__ __align__(16) unsigned short h[64*HSTR];   // 25600 B
    int l = threadIdx.x & 63, w = threadIdx.x >> 6;
    int c = l & 15, g = l >> 4;
    size_t m0 = (size_t)blockIdx.x*64;
    bf16x8 bx[4][6];
    #pragma unroll
    for (int mt = 0; mt < 4; ++mt){
        const float* ar = xln + (m0 + mt*16 + c)*DIMC;
        #pragma unroll
        for (int s = 0; s < 6; ++s){
            int k0 = s*32 + g*8;
            bx[mt][s] = pack8(*(const float4*)(ar + k0), *(const float4*)(ar + k0 + 4));
        }
    }
    f32x4 acc[4][3];
    #pragma unroll
    for (int jj = 0; jj < 3; ++jj){
        float4 b4 = *(const float4*)(b2 + (3*w + jj)*16 + g*4);
        f32x4 v = {b4.x, b4.y, b4.z, b4.w};
        #pragma unroll
        for (int mt = 0; mt < 4; ++mt) acc[mt][jj] = v;
    }
    for (int ch = 0; ch < 4; ++ch){
        #pragma unroll
        for (int jj = 0; jj < 3; ++jj){
            int j = ch*12 + 3*w + jj;
            float4 b40 = *(const float4*)(b1 + j*16 + g*4);
            f32x4 a0 = {b40.x, b40.y, b40.z, b40.w};
            f32x4 a1 = a0, a2 = a0, a3 = a0;
            const bf16x8* wp = (const bf16x8*)(W1p + ((size_t)(j*6)*64 + l)*8);
            #pragma unroll
            for (int s = 0; s < 6; ++s){
                bf16x8 wfr = wp[s*64];
                a0 = __builtin_amdgcn_mfma_f32_16x16x32_bf16(wfr, bx[0][s], a0, 0, 0, 0);
                a1 = __builtin_amdgcn_mfma_f32_16x16x32_bf16(wfr, bx[1][s], a1, 0, 0, 0);
                a2 = __builtin_amdgcn_mfma_f32_16x16x32_bf16(wfr, bx[2][s], a2, 0, 0, 0);
                a3 = __builtin_amdgcn_mfma_f32_16x16x32_bf16(wfr, bx[3][s], a3, 0, 0, 0);
            }
            int fb = (3*w + jj)*16 + g*4;
            ushort4 u;
            u.x=f2bf(gelu_f(a0[0])); u.y=f2bf(gelu_f(a0[1]));
            u.z=f2bf(gelu_f(a0[2])); u.w=f2bf(gelu_f(a0[3]));
            *(ushort4*)(h + (0*16 + c)*HSTR + fb) = u;
            u.x=f2bf(gelu_f(a1[0])); u.y=f2bf(gelu_f(a1[1]));
            u.z=f2bf(gelu_f(a1[2])); u.w=f2bf(gelu_f(a1[3]));
            *(ushort4*)(h + (1*16 + c)*HSTR + fb) = u;
            u.x=f2bf(gelu_f(a2[0])); u.y=f2bf(gelu_f(a2[1]));
            u.z=f2bf(gelu_f(a2[2])); u.w=f2bf(gelu_f(a2[3]));
            *(ushort4*)(h + (2*16 + c)*HSTR + fb) = u;
            u.x=f2bf(gelu_f(a3[0])); u.y=f2bf(gelu_f(a3[1]));
            u.z=f2bf(gelu_f(a3[2])); u.w=f2bf(gelu_f(a3[3]));
            *(ushort4*)(h + (3*16 + c)*HSTR + fb) = u;
        }
        __syncthreads();
        #pragma unroll
        for (int s = 0; s < 6; ++s){
            bf16x8 hf[4];
            #pragma unroll
            for (int mt = 0; mt < 4; ++mt)
                hf[mt] = *(const bf16x8*)(h + (mt*16 + c)*HSTR + s*32 + g*8);
            #pragma unroll
            for (int jj = 0; jj < 3; ++jj){
                int j = 3*w + jj;
                bf16x8 wf = *(const bf16x8*)(W2p + ((size_t)(j*24 + ch*6 + s)*64 + l)*8);
                #pragma unroll
                for (int mt = 0; mt < 4; ++mt)
                    acc[mt][jj] = __builtin_amdgcn_mfma_f32_16x16x32_bf16(wf, hf[mt], acc[mt][jj], 0, 0, 0);
            }
        }
        __syncthreads();
    }
    #pragma unroll
    for (int mt = 0; mt < 4; ++mt){
        #pragma unroll
        for (int jj = 0; jj < 3; ++jj){
            size_t o = (m0 + mt*16 + c)*DIMC + (3*w + jj)*16 + g*4;
            float4 r = *(const float4*)(xout + o);
            *(float4*)(xout + o) = make_float4(acc[mt][jj][0]+r.x, acc[mt][jj][1]+r.y,
                                               acc[mt][jj][2]+r.z, acc[mt][jj][3]+r.w);
        }
    }
}

// ---------------- fused qkv + window attention, all-MFMA (r7-verified)
__global__ __launch_bounds__(512, 2) void attn_fused_kernel(
    float* __restrict__ xio, const unsigned short* __restrict__ Wp,
    const float* __restrict__ bias, const float* __restrict__ qg,
    const float* __restrict__ rpb, int F)
{
    __shared__ __align__(16) unsigned short q_lds[64*QSTR];  // 26624 B
    __shared__ __align__(16) unsigned short k_lds[64*QSTR];  // 26624 B
    __shared__ __align__(16) unsigned short vt[192*VSTR];    // 30720 B
    __shared__ __align__(16) unsigned short pp[8*16*PSTR];   // 20480 B
    __shared__ float sinv_l[8*16];
    __shared__ float rpb_l[NHEADS*169];
    int tid = threadIdx.x;
    int w8 = tid >> 6;
    int l = tid & 63, c = l & 15, g = l >> 4;
    int blk = blockIdx.x;
    int b = blk >> 4, win = blk & 15;
    int wr = win >> 2, wc = win & 3;
    bool isglobal = (F == 384);

    for (int i = tid; i < 15*QSTR; i += 512){
        q_lds[49*QSTR + i] = 0; k_lds[49*QSTR + i] = 0;
    }
    for (int i = tid; i < 192*15; i += 512){
        int d = i / 15, t = 49 + (i - d*15);
        vt[d*VSTR + t] = 0;
    }
    for (int i = tid; i < NHEADS*169; i += 512){
        int hd = i / 169, r = i - hd*169;
        rpb_l[i] = rpb[r*NHEADS + hd];
    }

    // ---- phase 1: qkv projection via MFMA
    {
        bf16x8 bx[4][6];
        #pragma unroll
        for (int mt = 0; mt < 4; ++mt){
            int t = mt*16 + c;
            if (t < NTOK){
                int hh = wr*WSZ + t/WSZ, ww = wc*WSZ + t - (t/WSZ)*WSZ;
                const float* ar = xio + (((size_t)b*RESX + hh)*RESX + ww)*DIMC;
                #pragma unroll
                for (int s = 0; s < 6; ++s){
                    int k0 = s*32 + g*8;
                    bx[mt][s] = pack8(*(const float4*)(ar + k0), *(const float4*)(ar + k0 + 4));
                }
            } else {
                bf16x8 z = {0,0,0,0,0,0,0,0};
                #pragma unroll
                for (int s = 0; s < 6; ++s) bx[mt][s] = z;
            }
        }
        int ntile = F >> 4;    // 36 local / 24 global
        for (int jn = w8; jn < ntile; jn += 8){
            float4 bb4 = *(const float4*)(bias + jn*16 + g*4);
            f32x4 a0 = {bb4.x, bb4.y, bb4.z, bb4.w};
            f32x4 a1 = a0, a2 = a0, a3 = a0;
            const bf16x8* wp = (const bf16x8*)(Wp + ((size_t)(jn*6)*64 + l)*8);
            #pragma unroll
            for (int s = 0; s < 6; ++s){
                bf16x8 wfr = wp[s*64];
                a0 = __builtin_amdgcn_mfma_f32_16x16x32_bf16(wfr, bx[0][s], a0, 0, 0, 0);
                a1 = __builtin_amdgcn_mfma_f32_16x16x32_bf16(wfr, bx[1][s], a1, 0, 0, 0);
                a2 = __builtin_amdgcn_mfma_f32_16x16x32_bf16(wfr, bx[2][s], a2, 0, 0, 0);
                a3 = __builtin_amdgcn_mfma_f32_16x16x32_bf16(wfr, bx[3][s], a3, 0, 0, 0);
            }
            int sect = jn / 12 + (isglobal ? 1 : 0);   // 0=q,1=k,2=v
            int frel = (jn - (jn/12)*12)*16 + g*4;
            f32x4 av[4] = {a0, a1, a2, a3};
            #pragma unroll
            for (int mt = 0; mt < 4; ++mt){
                int t = mt*16 + c;
                if (t >= NTOK) continue;
                f32x4 a = av[mt];
                if (sect == 0){
                    ushort4 u;
                    u.x=f2bf(a[0]*SCALE); u.y=f2bf(a[1]*SCALE);
                    u.z=f2bf(a[2]*SCALE); u.w=f2bf(a[3]*SCALE);
                    *(ushort4*)(q_lds + t*QSTR + frel) = u;
                } else if (sect == 1){
                    ushort4 u;
                    u.x=f2bf(a[0]); u.y=f2bf(a[1]); u.z=f2bf(a[2]); u.w=f2bf(a[3]);
                    *(ushort4*)(k_lds + t*QSTR + frel) = u;
                } else {
                    vt[(frel+0)*VSTR + t] = f2bf(a[0]);
                    vt[(frel+1)*VSTR + t] = f2bf(a[1]);
                    vt[(frel+2)*VSTR + t] = f2bf(a[2]);
                    vt[(frel+3)*VSTR + t] = f2bf(a[3]);
                }
            }
        }
        if (isglobal){
            for (int i = tid; i < NTOK*48; i += 512){
                int t = i / 48, f4 = i - (i/48)*48;
                float4 qv = *(const float4*)(qg + ((size_t)b*NTOK + t)*DIMC + f4*4);
                ushort4 u;
                u.x=f2bf(qv.x*SCALE); u.y=f2bf(qv.y*SCALE);
                u.z=f2bf(qv.z*SCALE); u.w=f2bf(qv.w*SCALE);
                *(ushort4*)(q_lds + t*QSTR + f4*4) = u;
            }
        }
    }
    __syncthreads();

    // ---- 24 attention units, 3 per wave (pp/sinv rows wave-private: no barriers)
    for (int uu = 0; uu < 3; ++uu){
        int unit = w8*3 + uu;
        int ti = unit / 6, hd = unit - (unit/6)*6;
        bf16x8 qa = *(const bf16x8*)(q_lds + (16*ti + c)*QSTR + hd*HD + g*8);
        f32x4 S[4];
        {
            const f32x4 z = {0.f, 0.f, 0.f, 0.f};
            #pragma unroll
            for (int tj = 0; tj < 4; ++tj){
                bf16x8 kb = *(const bf16x8*)(k_lds + (16*tj + c)*QSTR + hd*HD + g*8);
                S[tj] = __builtin_amdgcn_mfma_f32_16x16x32_bf16(qa, kb, z, 0, 0, 0);
            }
        }
        float tot[4] = {0.f, 0.f, 0.f, 0.f};
        unsigned short pu[4][4];
        int ibase = 16*ti + g*4;
        #pragma unroll
        for (int tj = 0; tj < 4; ++tj){
            int j = 16*tj + c;
            bool jok = (j < NTOK);
            int jc = jok ? j : 0;
            int rj = jc / 7, cj = jc - rj*7;
            #pragma unroll
            for (int r = 0; r < 4; ++r){
                int i = ibase + r;
                int ic = (i < NTOK) ? i : 0;
                int ri = ic / 7, ci = ic - ri*7;
                unsigned short u16 = 0;
                if (jok){
                    float bv = rpb_l[hd*169 + (ri - rj + 6)*13 + (ci - cj + 6)];
                    u16 = f2bf(__expf(S[tj][r] + bv));
                }
                pu[tj][r] = u16;
                tot[r] += bf2f(u16);
            }
        }
        #pragma unroll
        for (int r = 0; r < 4; ++r){
            float t0 = tot[r];
            t0 += __shfl_xor(t0, 1); t0 += __shfl_xor(t0, 2);
            t0 += __shfl_xor(t0, 4); t0 += __shfl_xor(t0, 8);
            tot[r] = t0;
        }
        if (c == 0){
            #pragma unroll
            for (int r = 0; r < 4; ++r)
                sinv_l[w8*16 + g*4 + r] = 1.0f / tot[r];
        }
        #pragma unroll
        for (int tj = 0; tj < 4; ++tj){
            #pragma unroll
            for (int r = 0; r < 4; ++r)
                pp[(w8*16 + g*4 + r)*PSTR + 16*tj + c] = pu[tj][r];
        }
        bf16x8 pb0 = *(const bf16x8*)(pp + (w8*16 + c)*PSTR + g*8);
        bf16x8 pb1 = *(const bf16x8*)(pp + (w8*16 + c)*PSTR + 32 + g*8);
        float si = sinv_l[w8*16 + c];
        int t = 16*ti + c;
        #pragma unroll
        for (int dm = 0; dm < 2; ++dm){
            int vrow = hd*HD + dm*16 + c;
            bf16x8 va0 = *(const bf16x8*)(vt + vrow*VSTR + g*8);
            bf16x8 va1 = *(const bf16x8*)(vt + vrow*VSTR + 32 + g*8);
            const f32x4 z = {0.f, 0.f, 0.f, 0.f};
            f32x4 o = __builtin_amdgcn_mfma_f32_16x16x32_bf16(va0, pb0, z, 0, 0, 0);
            o = __builtin_amdgcn_mfma_f32_16x16x32_bf16(va1, pb1, o, 0, 0, 0);
            if (t < NTOK){
                int hh = wr*WSZ + t/WSZ, ww = wc*WSZ + t - (t/WSZ)*WSZ;
                float4 ov = make_float4(o[0]*si, o[1]*si, o[2]*si, o[3]*si);
                *(float4*)(xio + (((size_t)b*RESX + hh)*RESX + ww)*DIMC
                           + hd*HD + dm*16 + g*4) = ov;
            }
        }
    }
}

static inline int pick_ppw(int M){
    int ppw = M / 65536;                 // target >= ~512 blocks (2 per CU)
    if (ppw < 1) ppw = 1;
    if (ppw > 8) ppw = 8;
    return ppw;
}

extern "C" void kernel_launch(void* const* d_in, const int* in_sizes, int n_in,
                              void* d_out, int out_size, void* d_ws, size_t ws_size,
                              hipStream_t stream)
{
    (void)in_sizes; (void)n_in; (void)out_size;
    const float* x = (const float*)d_in[0];
    const float* fe_dw[2]  = {(const float*)d_in[1], (const float*)d_in[5]};
    const float* fe_se1[2] = {(const float*)d_in[2], (const float*)d_in[6]};
    const float* fe_se2[2] = {(const float*)d_in[3], (const float*)d_in[7]};
    const float* fe_pw[2]  = {(const float*)d_in[4], (const float*)d_in[8]};
    const float* n1g[2]  = {(const float*)d_in[9],  (const float*)d_in[22]};
    const float* n1b[2]  = {(const float*)d_in[10], (const float*)d_in[23]};
    const float* qkvw[2] = {(const float*)d_in[11], (const float*)d_in[24]};
    const float* qkvb[2] = {(const float*)d_in[12], (const float*)d_in[25]};
    const float* rpb[2]  = {(const float*)d_in[13], (const float*)d_in[26]};
    const float* prjw[2] = {(const float*)d_in[14], (const float*)d_in[27]};
    const float* prjb[2] = {(const float*)d_in[15], (const float*)d_in[28]};
    const float* n2g[2]  = {(const float*)d_in[16], (const float*)d_in[29]};
    const float* n2b[2]  = {(const float*)d_in[17], (const float*)d_in[30]};
    const float* fc1w[2] = {(const float*)d_in[18], (const float*)d_in[31]};
    const float* fc1b[2] = {(const float*)d_in[19], (const float*)d_in[32]};
    const float* fc2w[2] = {(const float*)d_in[20], (const float*)d_in[33]};
    const float* fc2b[2] = {(const float*)d_in[21], (const float*)d_in[34]};

    float* out = (float*)d_out;
    float* ws = (float*)d_ws;
    const size_t n28 = (size_t)NB*RESX*RESX*DIMC;     // 19,267,584
    const size_t n14 = (size_t)NB*14*14*DIMC;         //  4,816,896
    const size_t n7  = (size_t)NB*7*7*DIMC;           //  1,204,224
    float* region0 = ws;
    float* x7      = region0 + n28;      // also SE-partials scratch during phase A
    float* s0      = x7 + n7;
    float* s1      = s0 + NB*DIMC;
    float* pwpk_f  = s1 + NB*DIMC;       // 2 packed pw weights
    float* dyn     = pwpk_f + 36864;     // phase A: x14 ; phase B: packed weights
    size_t fixedf  = n28 + n7 + 2ull*NB*DIMC + 36864;
    if (ws_size < (fixedf + n14) * sizeof(float)) return;
    float* x14 = dyn;
    unsigned short* pwpk = (unsigned short*)pwpk_f;

    unsigned short* pk = (unsigned short*)dyn;
    const size_t PK_QKV0 = 0;                 // 576x192
    const size_t PK_QKV1 = PK_QKV0 + 576*192; // 384x192
    const size_t PK_PRJ0 = PK_QKV1 + 384*192;
    const size_t PK_PRJ1 = PK_PRJ0 + 192*192;
    const size_t PK_FC10 = PK_PRJ1 + 192*192;
    const size_t PK_FC11 = PK_FC10 + 768*192;
    const size_t PK_FC20 = PK_FC11 + 768*192;
    const size_t PK_FC21 = PK_FC20 + 192*768; // total 847872 ushorts < n14 floats

    // ---- pack pw weights (2 segments, one launch)
    {
        PackArgs a = {};
        a.src[0] = fe_pw[0]; a.dst[0] = pwpk;         a.K[0] = 192; a.tEnd[0] = 4608;
        a.src[1] = fe_pw[1]; a.dst[1] = pwpk + 36864; a.K[1] = 192; a.tEnd[1] = 9216;
        a.nseg = 2;
        pack_multi_kernel<<<(9216 + 255)/256, 256, 0, stream>>>(a);
    }

    // ---- Phase A: GlobalQueryGen: 28 -> 14 -> 7
    for (int fe = 0; fe < 2; ++fe){
        int H = fe ? 14 : 28;
        int HW = H * H;
        int M = NB * HW;
        const float* src = fe ? x14 : x;
        float* dst = fe ? x7 : x14;
        dw_gelu_kernel<<<NB*HW, DIMC, 0, stream>>>(src, fe_dw[fe], region0, H, H);
        se_reduce_kernel<<<NB*SEPARTS, DIMC, 0, stream>>>(region0, x7, HW);
        se_mlp_kernel<<<NB, DIMC, 0, stream>>>(x7, fe_se1[fe], fe_se2[fe], s1, HW);
        int ppw = pick_ppw(M);
        dim3 ga((M + 128*ppw - 1) / (128*ppw), 1);
        gemmW_kernel<<<ga, 256, 0, stream>>>(region0, pwpk + fe*36864, nullptr,
                                             src, region0, DIMC, M, ppw, s1, HW);
        maxpool_kernel<<<NB*(H/2)*(H/2), DIMC, 0, stream>>>(region0, dst, H, H);
    }

    // ---- pack remaining weights (8 segments, one launch; x14 dead now)
    {
        PackArgs a = {};
        const float* srcs[8] = {qkvw[0], qkvw[1], prjw[0], prjw[1],
                                fc1w[0], fc1w[1], fc2w[0], fc2w[1]};
        size_t offs[8] = {PK_QKV0, PK_QKV1, PK_PRJ0, PK_PRJ1,
                          PK_FC10, PK_FC11, PK_FC20, PK_FC21};
        int kk[8]  = {192, 192, 192, 192, 192, 192, 768, 768};
        int cnt[8] = {13824, 9216, 4608, 4608, 18432, 18432, 18432, 18432};
        int cum = 0;
        for (int i = 0; i < 8; ++i){
            a.src[i] = srcs[i]; a.dst[i] = pk + offs[i]; a.K[i] = kk[i];
            cum += cnt[i]; a.tEnd[i] = cum;
        }
        a.nseg = 8;
        pack_multi_kernel<<<(cum + 255)/256, 256, 0, stream>>>(a);
    }

    // ---- Phase B: two attention blocks (0=local, 1=global query)
    for (int blk = 0; blk < 2; ++blk){
        const float* xin = blk ? (const float*)out : x;
        ln_kernel<<<TOK28/4, 256, 0, stream>>>(xin, n1g[blk], n1b[blk], region0);
        int F = blk ? 384 : 576;
        attn_fused_kernel<<<NB*16, 512, 0, stream>>>(
            region0, pk + (blk ? PK_QKV1 : PK_QKV0), qkvb[blk],
            blk ? x7 : nullptr, rpb[blk], F);
        {
            int M = TOK28;
            int ppw = pick_ppw(M);
            dim3 gp((M + 128*ppw - 1) / (128*ppw), 1);
            gemmW_kernel<<<gp, 256, 0, stream>>>(region0,
                pk + (blk ? PK_PRJ1 : PK_PRJ0), prjb[blk], xin, out,
                DIMC, M, ppw, nullptr, 0);
        }
        ln_kernel<<<TOK28/4, 256, 0, stream>>>(out, n2g[blk], n2b[blk], region0);
        mlp_mfma_kernel<<<TOK28/64, 256, 0, stream>>>(region0,
            pk + (blk ? PK_FC11 : PK_FC10), fc1b[blk],
            pk + (blk ? PK_FC21 : PK_FC20), fc2b[blk], out);
    }
}

// Round 14
// 1261.159 us; speedup vs baseline: 1.4032x; 1.0040x over previous
//
#include <hip/hip_runtime.h>
#include <hip/hip_bf16.h>
#include <math.h>

#define NB     128
#define RESX   28
#define DIMC   192
#define NHEADS 6
#define WSZ    7
#define HD     32
#define NTOK   49
#define SCALE  0.17677669529663687f   // 32^-0.5
#define TOK28  (NB*RESX*RESX)         // 100352
#define QSTR   208                    // ushorts per q/k row
#define VSTR   80                     // ushorts per vt row
#define PSTR   80                     // ushorts per P row
#define HSTR   200                    // ushorts per h row (r7-verified)
#define SEPARTS 8

typedef short    bf16x8 __attribute__((ext_vector_type(8)));
typedef float    f32x4  __attribute__((ext_vector_type(4)));

__device__ __forceinline__ float gelu_f(float x){          // exact erf GELU (r7-verified)
    return 0.5f * x * (1.0f + erff(x * 0.70710678118654752f));
}
__device__ __forceinline__ unsigned short f2bf(float f){
    unsigned int u = __float_as_uint(f);
    u += 0x7fffu + ((u >> 16) & 1u);          // RNE
    return (unsigned short)(u >> 16);
}
__device__ __forceinline__ float bf2f(unsigned short u){
    return __uint_as_float(((unsigned int)u) << 16);
}
__device__ __forceinline__ bf16x8 pack8(float4 u, float4 v){
    bf16x8 r;
    r[0]=(short)f2bf(u.x); r[1]=(short)f2bf(u.y); r[2]=(short)f2bf(u.z); r[3]=(short)f2bf(u.w);
    r[4]=(short)f2bf(v.x); r[5]=(short)f2bf(v.y); r[6]=(short)f2bf(v.z); r[7]=(short)f2bf(v.w);
    return r;
}

// ---------------- LayerNorm: one wave per token (4 tokens / 256-thread block)
__global__ __launch_bounds__(256) void ln_kernel(const float* __restrict__ x,
        const float* __restrict__ g, const float* __restrict__ be,
        float* __restrict__ out)
{
    int wid = threadIdx.x >> 6, lane = threadIdx.x & 63;
    size_t tok = (size_t)blockIdx.x * 4 + wid;
    const float* xr = x + tok * DIMC;
    float v0 = xr[lane], v1 = xr[lane + 64], v2 = xr[lane + 128];
    float s  = v0 + v1 + v2;
    float sq = v0*v0 + v1*v1 + v2*v2;
    #pragma unroll
    for (int o = 32; o > 0; o >>= 1){ s += __shfl_xor(s, o); sq += __shfl_xor(sq, o); }
    float mean = s * (1.0f/DIMC);
    float var  = sq * (1.0f/DIMC) - mean*mean;
    float rstd = rsqrtf(var + 1e-5f);
    float* orow = out + tok * DIMC;
    orow[lane]     = (v0-mean)*rstd*g[lane]     + be[lane];
    orow[lane+64]  = (v1-mean)*rstd*g[lane+64]  + be[lane+64];
    orow[lane+128] = (v2-mean)*rstd*g[lane+128] + be[lane+128];
}

// ---------------- depthwise 3x3 (NHWC) + exact GELU
__global__ void dw_gelu_kernel(const float* __restrict__ x, const float* __restrict__ dw,
                               float* __restrict__ y, int H, int W)
{
    int p = blockIdx.x;
    int c = threadIdx.x;
    int w = p % W; int h = (p / W) % H; int b = p / (W*H);
    const float* base = x + (size_t)b*H*W*DIMC;
    float acc = 0.f;
    #pragma unroll
    for (int kh = 0; kh < 3; ++kh){
        int hh = h + kh - 1; if (hh < 0 || hh >= H) continue;
        #pragma unroll
        for (int kw = 0; kw < 3; ++kw){
            int ww = w + kw - 1; if (ww < 0 || ww >= W) continue;
            acc += base[((size_t)hh*W + ww)*DIMC + c] * dw[c*9 + kh*3 + kw];
        }
    }
    y[(size_t)p*DIMC + c] = gelu_f(acc);
}

// ---------------- SE: partial average pool (SEPARTS blocks per image)
__global__ void se_reduce_kernel(const float* __restrict__ y, float* __restrict__ part,
                                 int HW)
{
    int blk = blockIdx.x;                 // b*SEPARTS + i
    int b = blk / SEPARTS, i = blk - b*SEPARTS;
    int c = threadIdx.x;
    int chunk = (HW + SEPARTS - 1) / SEPARTS;
    int p0 = i*chunk, p1 = p0 + chunk;
    if (p1 > HW) p1 = HW;
    const float* base = y + (size_t)b*HW*DIMC + c;
    float acc = 0.f;
    for (int p = p0; p < p1; ++p) acc += base[(size_t)p*DIMC];
    part[(size_t)blk*DIMC + c] = acc;
}

// ---------------- SE: merge partials -> 192 -> gelu(48) -> sigmoid(192)
__global__ void se_mlp_kernel(const float* __restrict__ part, const float* __restrict__ w1,
                              const float* __restrict__ w2, float* __restrict__ s, int HW)
{
    __shared__ float sl[DIMC];
    __shared__ float mid[48];
    int b = blockIdx.x; int t = threadIdx.x;
    float acc0 = 0.f;
    #pragma unroll
    for (int i = 0; i < SEPARTS; ++i)
        acc0 += part[((size_t)b*SEPARTS + i)*DIMC + t];
    sl[t] = acc0 / (float)HW;
    __syncthreads();
    if (t < 48){
        float acc = 0.f;
        for (int c = 0; c < DIMC; ++c) acc += sl[c] * w1[t*DIMC + c];
        mid[t] = gelu_f(acc);
    }
    __syncthreads();
    float acc = 0.f;
    #pragma unroll 8
    for (int j = 0; j < 48; ++j) acc += mid[j] * w2[t*48 + j];
    s[b*DIMC + t] = 1.0f / (1.0f + expf(-acc));
}

// ---------------- maxpool 3x3 stride 2 pad 1 (NHWC)
__global__ void maxpool_kernel(const float* __restrict__ x, float* __restrict__ out,
                               int H, int W)
{
    int H2 = H >> 1, W2 = W >> 1;
    int p = blockIdx.x;
    int c = threadIdx.x;
    int w2 = p % W2; int h2 = (p / W2) % H2; int b = p / (W2*H2);
    float m = -INFINITY;
    #pragma unroll
    for (int dh = -1; dh <= 1; ++dh){
        int h = 2*h2 + dh; if (h < 0 || h >= H) continue;
        #pragma unroll
        for (int dw = -1; dw <= 1; ++dw){
            int w = 2*w2 + dw; if (w < 0 || w >= W) continue;
            m = fmaxf(m, x[(((size_t)b*H + h)*W + w)*DIMC + c]);
        }
    }
    out[(size_t)p*DIMC + c] = m;
}

// ---------------- merged weight pack: up to 8 segments in one launch
struct PackArgs {
    const float* src[8];
    unsigned short* dst[8];
    int K[8];
    int tEnd[8];
    int nseg;
};
__global__ __launch_bounds__(256) void pack_multi_kernel(PackArgs a)
{
    int t = blockIdx.x*256 + threadIdx.x;
    int seg = 0;
    while (seg < a.nseg && t >= a.tEnd[seg]) ++seg;
    if (seg >= a.nseg) return;
    int t0 = seg ? a.tEnd[seg-1] : 0;
    int tl = t - t0;
    int lane = tl & 63, frag = tl >> 6;
    int K = a.K[seg], ks = K >> 5;
    int j = frag / ks, s = frag - j*ks;
    const float* wr = a.src[seg] + (size_t)(j*16 + (lane & 15))*K + s*32 + ((lane>>4)<<3);
    bf16x8 r = pack8(*(const float4*)wr, *(const float4*)(wr + 4));
    *((bf16x8*)(a.dst[seg] + (size_t)tl*8)) = r;
}

// ---------------- weight-stationary MFMA GEMM (K=192, N=192-chunked in LDS)
__global__ __launch_bounds__(256) void gemmW_kernel(
    const float* __restrict__ in, const unsigned short* __restrict__ Wp,
    const float* __restrict__ bias, const float* __restrict__ res,
    float* __restrict__ out, int N, int M, int ppw,
    const float* __restrict__ sv, int HW)
{
    __shared__ __align__(16) unsigned short wlds[72*512];  // 73728 B
    __shared__ __align__(16) float sbias[192];
    int tid = threadIdx.x;
    int l = tid & 63, w = tid >> 6, c = l & 15, g = l >> 4;
    int nc = blockIdx.y;
    const bf16x8* wsrc = (const bf16x8*)(Wp + (size_t)nc*36864);
    bf16x8* wdst = (bf16x8*)wlds;
    #pragma unroll 2
    for (int i = tid; i < 4608; i += 256) wdst[i] = wsrc[i];
    if (tid < 48){
        float4 bb = bias ? ((const float4*)(bias + nc*192))[tid]
                         : make_float4(0.f,0.f,0.f,0.f);
        ((float4*)sbias)[tid] = bb;
    }
    __syncthreads();
    size_t mbase = (size_t)blockIdx.x*(128*ppw) + (size_t)w*(32*ppw);
    for (int p = 0; p < ppw; ++p){
        size_t m0 = mbase + (size_t)p*32;
        if ((long)m0 >= M) break;
        bool st1 = (long)(m0 + 16) < M;
        const float* ar0 = in + (m0 + c)*DIMC;
        const float* ar1 = ar0 + 16*DIMC;
        bf16x8 b0[6], b1[6];
        #pragma unroll
        for (int s = 0; s < 6; ++s){
            int k0 = s*32 + g*8;
            float4 u0 = *(const float4*)(ar0 + k0), v0 = *(const float4*)(ar0 + k0 + 4);
            float4 u1 = *(const float4*)(ar1 + k0), v1 = *(const float4*)(ar1 + k0 + 4);
            if (sv){
                int bi0 = (int)((m0 + c)/HW), bi1 = (int)((m0 + 16 + c)/HW);
                float4 a0 = *(const float4*)(sv + (size_t)bi0*DIMC + k0);
                float4 a1 = *(const float4*)(sv + (size_t)bi0*DIMC + k0 + 4);
                float4 d0 = *(const float4*)(sv + (size_t)bi1*DIMC + k0);
                float4 d1 = *(const float4*)(sv + (size_t)bi1*DIMC + k0 + 4);
                u0.x*=a0.x; u0.y*=a0.y; u0.z*=a0.z; u0.w*=a0.w;
                v0.x*=a1.x; v0.y*=a1.y; v0.z*=a1.z; v0.w*=a1.w;
                u1.x*=d0.x; u1.y*=d0.y; u1.z*=d0.z; u1.w*=d0.w;
                v1.x*=d1.x; v1.y*=d1.y; v1.z*=d1.z; v1.w*=d1.w;
            }
            b0[s] = pack8(u0, v0);
            b1[s] = pack8(u1, v1);
        }
        #pragma unroll 2
        for (int j = 0; j < 12; ++j){
            float4 bb = *(const float4*)(sbias + j*16 + g*4);
            f32x4 a0 = {bb.x, bb.y, bb.z, bb.w};
            f32x4 a1 = a0;
            const bf16x8* wf = (const bf16x8*)wlds + (size_t)j*6*64 + l;
            #pragma unroll
            for (int s = 0; s < 6; ++s){
                bf16x8 wfr = wf[s*64];
                a0 = __builtin_amdgcn_mfma_f32_16x16x32_bf16(wfr, b0[s], a0, 0, 0, 0);
                a1 = __builtin_amdgcn_mfma_f32_16x16x32_bf16(wfr, b1[s], a1, 0, 0, 0);
            }
            int ncol = nc*192 + j*16 + g*4;
            size_t o0 = (m0 + c)*(size_t)N + ncol;
            size_t o1 = o0 + (size_t)16*N;
            float4 r0 = res ? *(const float4*)(res + o0) : make_float4(0.f,0.f,0.f,0.f);
            *(float4*)(out + o0) = make_float4(a0[0]+r0.x, a0[1]+r0.y, a0[2]+r0.z, a0[3]+r0.w);
            if (st1){
                float4 r1 = res ? *(const float4*)(res + o1) : make_float4(0.f,0.f,0.f,0.f);
                *(float4*)(out + o1) = make_float4(a1[0]+r1.x, a1[1]+r1.y, a1[2]+r1.z, a1[3]+r1.w);
            }
        }
    }
}

// ---------------- fused MFMA MLP v3 + double-buffered h (4 barriers, was 8)
__global__ __launch_bounds__(256, 2) void mlp_mfma_kernel(
    const float* __restrict__ xln,
    const unsigned short* __restrict__ W1p, const float* __restrict__ b1,
    const unsigned short* __restrict__ W2p, const float* __restrict__ b2,
    float* __restrict__ xout)
{
    __shared__ __align__(16) unsigned short h[2][64*HSTR];   // 51200 B
    int l = threadIdx.x & 63, w = threadIdx.x >> 6;
    int c = l & 15, g = l >> 4;
    size_t m0 = (size_t)blockIdx.x*64;
    bf16x8 bx[4][6];
    #pragma unroll
    for (int mt = 0; mt < 4; ++mt){
        const float* ar = xln + (m0 + mt*16 + c)*DIMC;
        #pragma unroll
        for (int s = 0; s < 6; ++s){
            int k0 = s*32 + g*8;
            bx[mt][s] = pack8(*(const float4*)(ar + k0), *(const float4*)(ar + k0 + 4));
        }
    }
    f32x4 acc[4][3];
    #pragma unroll
    for (int jj = 0; jj < 3; ++jj){
        float4 b4 = *(const float4*)(b2 + (3*w + jj)*16 + g*4);
        f32x4 v = {b4.x, b4.y, b4.z, b4.w};
        #pragma unroll
        for (int mt = 0; mt < 4; ++mt) acc[mt][jj] = v;
    }
    for (int ch = 0; ch < 4; ++ch){
        unsigned short* hb = &h[ch & 1][0];
        #pragma unroll
        for (int jj = 0; jj < 3; ++jj){
            int j = ch*12 + 3*w + jj;
            float4 b40 = *(const float4*)(b1 + j*16 + g*4);
            f32x4 a0 = {b40.x, b40.y, b40.z, b40.w};
            f32x4 a1 = a0, a2 = a0, a3 = a0;
            const bf16x8* wp = (const bf16x8*)(W1p + ((size_t)(j*6)*64 + l)*8);
            #pragma unroll
            for (int s = 0; s < 6; ++s){
                bf16x8 wfr = wp[s*64];
                a0 = __builtin_amdgcn_mfma_f32_16x16x32_bf16(wfr, bx[0][s], a0, 0, 0, 0);
                a1 = __builtin_amdgcn_mfma_f32_16x16x32_bf16(wfr, bx[1][s], a1, 0, 0, 0);
                a2 = __builtin_amdgcn_mfma_f32_16x16x32_bf16(wfr, bx[2][s], a2, 0, 0, 0);
                a3 = __builtin_amdgcn_mfma_f32_16x16x32_bf16(wfr, bx[3][s], a3, 0, 0, 0);
            }
            int fb = (3*w + jj)*16 + g*4;
            ushort4 u;
            u.x=f2bf(gelu_f(a0[0])); u.y=f2bf(gelu_f(a0[1]));
            u.z=f2bf(gelu_f(a0[2])); u.w=f2bf(gelu_f(a0[3]));
            *(ushort4*)(hb + (0*16 + c)*HSTR + fb) = u;
            u.x=f2bf(gelu_f(a1[0])); u.y=f2bf(gelu_f(a1[1]));
            u.z=f2bf(gelu_f(a1[2])); u.w=f2bf(gelu_f(a1[3]));
            *(ushort4*)(hb + (1*16 + c)*HSTR + fb) = u;
            u.x=f2bf(gelu_f(a2[0])); u.y=f2bf(gelu_f(a2[1]));
            u.z=f2bf(gelu_f(a2[2])); u.w=f2bf(gelu_f(a2[3]));
            *(ushort4*)(hb + (2*16 + c)*HSTR + fb) = u;
            u.x=f2bf(gelu_f(a3[0])); u.y=f2bf(gelu_f(a3[1]));
            u.z=f2bf(gelu_f(a3[2])); u.w=f2bf(gelu_f(a3[3]));
            *(ushort4*)(hb + (3*16 + c)*HSTR + fb) = u;
        }
        __syncthreads();      // writes of h[ch&1] visible; prior buffer reads were
                              // ordered before the previous iteration's barrier
        #pragma unroll
        for (int s = 0; s < 6; ++s){
            bf16x8 hf[4];
            #pragma unroll
            for (int mt = 0; mt < 4; ++mt)
                hf[mt] = *(const bf16x8*)(hb + (mt*16 + c)*HSTR + s*32 + g*8);
            #pragma unroll
            for (int jj = 0; jj < 3; ++jj){
                int j = 3*w + jj;
                bf16x8 wf = *(const bf16x8*)(W2p + ((size_t)(j*24 + ch*6 + s)*64 + l)*8);
                #pragma unroll
                for (int mt = 0; mt < 4; ++mt)
                    acc[mt][jj] = __builtin_amdgcn_mfma_f32_16x16x32_bf16(wf, hf[mt], acc[mt][jj], 0, 0, 0);
            }
        }
    }
    #pragma unroll
    for (int mt = 0; mt < 4; ++mt){
        #pragma unroll
        for (int jj = 0; jj < 3; ++jj){
            size_t o = (m0 + mt*16 + c)*DIMC + (3*w + jj)*16 + g*4;
            float4 r = *(const float4*)(xout + o);
            *(float4*)(xout + o) = make_float4(acc[mt][jj][0]+r.x, acc[mt][jj][1]+r.y,
                                               acc[mt][jj][2]+r.z, acc[mt][jj][3]+r.w);
        }
    }
}

// ---------------- fused qkv + window attention, all-MFMA (r7-verified + setprio)
__global__ __launch_bounds__(512, 2) void attn_fused_kernel(
    float* __restrict__ xio, const unsigned short* __restrict__ Wp,
    const float* __restrict__ bias, const float* __restrict__ qg,
    const float* __restrict__ rpb, int F)
{
    __shared__ __align__(16) unsigned short q_lds[64*QSTR];  // 26624 B
    __shared__ __align__(16) unsigned short k_lds[64*QSTR];  // 26624 B
    __shared__ __align__(16) unsigned short vt[192*VSTR];    // 30720 B
    __shared__ __align__(16) unsigned short pp[8*16*PSTR];   // 20480 B
    __shared__ float sinv_l[8*16];
    __shared__ float rpb_l[NHEADS*169];
    int tid = threadIdx.x;
    int w8 = tid >> 6;
    int l = tid & 63, c = l & 15, g = l >> 4;
    int blk = blockIdx.x;
    int b = blk >> 4, win = blk & 15;
    int wr = win >> 2, wc = win & 3;
    bool isglobal = (F == 384);

    for (int i = tid; i < 15*QSTR; i += 512){
        q_lds[49*QSTR + i] = 0; k_lds[49*QSTR + i] = 0;
    }
    for (int i = tid; i < 192*15; i += 512){
        int d = i / 15, t = 49 + (i - d*15);
        vt[d*VSTR + t] = 0;
    }
    for (int i = tid; i < NHEADS*169; i += 512){
        int hd = i / 169, r = i - hd*169;
        rpb_l[i] = rpb[r*NHEADS + hd];
    }

    // ---- phase 1: qkv projection via MFMA
    {
        bf16x8 bx[4][6];
        #pragma unroll
        for (int mt = 0; mt < 4; ++mt){
            int t = mt*16 + c;
            if (t < NTOK){
                int hh = wr*WSZ + t/WSZ, ww = wc*WSZ + t - (t/WSZ)*WSZ;
                const float* ar = xio + (((size_t)b*RESX + hh)*RESX + ww)*DIMC;
                #pragma unroll
                for (int s = 0; s < 6; ++s){
                    int k0 = s*32 + g*8;
                    bx[mt][s] = pack8(*(const float4*)(ar + k0), *(const float4*)(ar + k0 + 4));
                }
            } else {
                bf16x8 z = {0,0,0,0,0,0,0,0};
                #pragma unroll
                for (int s = 0; s < 6; ++s) bx[mt][s] = z;
            }
        }
        int ntile = F >> 4;    // 36 local / 24 global
        for (int jn = w8; jn < ntile; jn += 8){
            float4 bb4 = *(const float4*)(bias + jn*16 + g*4);
            f32x4 a0 = {bb4.x, bb4.y, bb4.z, bb4.w};
            f32x4 a1 = a0, a2 = a0, a3 = a0;
            const bf16x8* wp = (const bf16x8*)(Wp + ((size_t)(jn*6)*64 + l)*8);
            #pragma unroll
            for (int s = 0; s < 6; ++s){
                bf16x8 wfr = wp[s*64];
                a0 = __builtin_amdgcn_mfma_f32_16x16x32_bf16(wfr, bx[0][s], a0, 0, 0, 0);
                a1 = __builtin_amdgcn_mfma_f32_16x16x32_bf16(wfr, bx[1][s], a1, 0, 0, 0);
                a2 = __builtin_amdgcn_mfma_f32_16x16x32_bf16(wfr, bx[2][s], a2, 0, 0, 0);
                a3 = __builtin_amdgcn_mfma_f32_16x16x32_bf16(wfr, bx[3][s], a3, 0, 0, 0);
            }
            int sect = jn / 12 + (isglobal ? 1 : 0);   // 0=q,1=k,2=v
            int frel = (jn - (jn/12)*12)*16 + g*4;
            f32x4 av[4] = {a0, a1, a2, a3};
            #pragma unroll
            for (int mt = 0; mt < 4; ++mt){
                int t = mt*16 + c;
                if (t >= NTOK) continue;
                f32x4 a = av[mt];
                if (sect == 0){
                    ushort4 u;
                    u.x=f2bf(a[0]*SCALE); u.y=f2bf(a[1]*SCALE);
                    u.z=f2bf(a[2]*SCALE); u.w=f2bf(a[3]*SCALE);
                    *(ushort4*)(q_lds + t*QSTR + frel) = u;
                } else if (sect == 1){
                    ushort4 u;
                    u.x=f2bf(a[0]); u.y=f2bf(a[1]); u.z=f2bf(a[2]); u.w=f2bf(a[3]);
                    *(ushort4*)(k_lds + t*QSTR + frel) = u;
                } else {
                    vt[(frel+0)*VSTR + t] = f2bf(a[0]);
                    vt[(frel+1)*VSTR + t] = f2bf(a[1]);
                    vt[(frel+2)*VSTR + t] = f2bf(a[2]);
                    vt[(frel+3)*VSTR + t] = f2bf(a[3]);
                }
            }
        }
        if (isglobal){
            for (int i = tid; i < NTOK*48; i += 512){
                int t = i / 48, f4 = i - (i/48)*48;
                float4 qv = *(const float4*)(qg + ((size_t)b*NTOK + t)*DIMC + f4*4);
                ushort4 u;
                u.x=f2bf(qv.x*SCALE); u.y=f2bf(qv.y*SCALE);
                u.z=f2bf(qv.z*SCALE); u.w=f2bf(qv.w*SCALE);
                *(ushort4*)(q_lds + t*QSTR + f4*4) = u;
            }
        }
    }
    __syncthreads();

    // ---- 24 attention units, 3 per wave (barrier-free; waves role-diverge ->
    //      setprio around MFMA clusters pays here, not in lockstep phase 1)
    for (int uu = 0; uu < 3; ++uu){
        int unit = w8*3 + uu;
        int ti = unit / 6, hd = unit - (unit/6)*6;
        bf16x8 qa = *(const bf16x8*)(q_lds + (16*ti + c)*QSTR + hd*HD + g*8);
        f32x4 S[4];
        {
            const f32x4 z = {0.f, 0.f, 0.f, 0.f};
            __builtin_amdgcn_s_setprio(1);
            #pragma unroll
            for (int tj = 0; tj < 4; ++tj){
                bf16x8 kb = *(const bf16x8*)(k_lds + (16*tj + c)*QSTR + hd*HD + g*8);
                S[tj] = __builtin_amdgcn_mfma_f32_16x16x32_bf16(qa, kb, z, 0, 0, 0);
            }
            __builtin_amdgcn_s_setprio(0);
        }
        float tot[4] = {0.f, 0.f, 0.f, 0.f};
        unsigned short pu[4][4];
        int ibase = 16*ti + g*4;
        #pragma unroll
        for (int tj = 0; tj < 4; ++tj){
            int j = 16*tj + c;
            bool jok = (j < NTOK);
            int jc = jok ? j : 0;
            int rj = jc / 7, cj = jc - rj*7;
            #pragma unroll
            for (int r = 0; r < 4; ++r){
                int i = ibase + r;
                int ic = (i < NTOK) ? i : 0;
                int ri = ic / 7, ci = ic - ri*7;
                unsigned short u16 = 0;
                if (jok){
                    float bv = rpb_l[hd*169 + (ri - rj + 6)*13 + (ci - cj + 6)];
                    u16 = f2bf(__expf(S[tj][r] + bv));
                }
                pu[tj][r] = u16;
                tot[r] += bf2f(u16);
            }
        }
        #pragma unroll
        for (int r = 0; r < 4; ++r){
            float t0 = tot[r];
            t0 += __shfl_xor(t0, 1); t0 += __shfl_xor(t0, 2);
            t0 += __shfl_xor(t0, 4); t0 += __shfl_xor(t0, 8);
            tot[r] = t0;
        }
        if (c == 0){
            #pragma unroll
            for (int r = 0; r < 4; ++r)
                sinv_l[w8*16 + g*4 + r] = 1.0f / tot[r];
        }
        #pragma unroll
        for (int tj = 0; tj < 4; ++tj){
            #pragma unroll
            for (int r = 0; r < 4; ++r)
                pp[(w8*16 + g*4 + r)*PSTR + 16*tj + c] = pu[tj][r];
        }
        bf16x8 pb0 = *(const bf16x8*)(pp + (w8*16 + c)*PSTR + g*8);
        bf16x8 pb1 = *(const bf16x8*)(pp + (w8*16 + c)*PSTR + 32 + g*8);
        float si = sinv_l[w8*16 + c];
        int t = 16*ti + c;
        #pragma unroll
        for (int dm = 0; dm < 2; ++dm){
            int vrow = hd*HD + dm*16 + c;
            bf16x8 va0 = *(const bf16x8*)(vt + vrow*VSTR + g*8);
            bf16x8 va1 = *(const bf16x8*)(vt + vrow*VSTR + 32 + g*8);
            const f32x4 z = {0.f, 0.f, 0.f, 0.f};
            __builtin_amdgcn_s_setprio(1);
            f32x4 o = __builtin_amdgcn_mfma_f32_16x16x32_bf16(va0, pb0, z, 0, 0, 0);
            o = __builtin_amdgcn_mfma_f32_16x16x32_bf16(va1, pb1, o, 0, 0, 0);
            __builtin_amdgcn_s_setprio(0);
            if (t < NTOK){
                int hh = wr*WSZ + t/WSZ, ww = wc*WSZ + t - (t/WSZ)*WSZ;
                float4 ov = make_float4(o[0]*si, o[1]*si, o[2]*si, o[3]*si);
                *(float4*)(xio + (((size_t)b*RESX + hh)*RESX + ww)*DIMC
                           + hd*HD + dm*16 + g*4) = ov;
            }
        }
    }
}

static inline int pick_ppw(int M){
    int ppw = M / 65536;                 // target >= ~512 blocks (2 per CU)
    if (ppw < 1) ppw = 1;
    if (ppw > 8) ppw = 8;
    return ppw;
}

extern "C" void kernel_launch(void* const* d_in, const int* in_sizes, int n_in,
                              void* d_out, int out_size, void* d_ws, size_t ws_size,
                              hipStream_t stream)
{
    (void)in_sizes; (void)n_in; (void)out_size;
    const float* x = (const float*)d_in[0];
    const float* fe_dw[2]  = {(const float*)d_in[1], (const float*)d_in[5]};
    const float* fe_se1[2] = {(const float*)d_in[2], (const float*)d_in[6]};
    const float* fe_se2[2] = {(const float*)d_in[3], (const float*)d_in[7]};
    const float* fe_pw[2]  = {(const float*)d_in[4], (const float*)d_in[8]};
    const float* n1g[2]  = {(const float*)d_in[9],  (const float*)d_in[22]};
    const float* n1b[2]  = {(const float*)d_in[10], (const float*)d_in[23]};
    const float* qkvw[2] = {(const float*)d_in[11], (const float*)d_in[24]};
    const float* qkvb[2] = {(const float*)d_in[12], (const float*)d_in[25]};
    const float* rpb[2]  = {(const float*)d_in[13], (const float*)d_in[26]};
    const float* prjw[2] = {(const float*)d_in[14], (const float*)d_in[27]};
    const float* prjb[2] = {(const float*)d_in[15], (const float*)d_in[28]};
    const float* n2g[2]  = {(const float*)d_in[16], (const float*)d_in[29]};
    const float* n2b[2]  = {(const float*)d_in[17], (const float*)d_in[30]};
    const float* fc1w[2] = {(const float*)d_in[18], (const float*)d_in[31]};
    const float* fc1b[2] = {(const float*)d_in[19], (const float*)d_in[32]};
    const float* fc2w[2] = {(const float*)d_in[20], (const float*)d_in[33]};
    const float* fc2b[2] = {(const float*)d_in[21], (const float*)d_in[34]};

    float* out = (float*)d_out;
    float* ws = (float*)d_ws;
    const size_t n28 = (size_t)NB*RESX*RESX*DIMC;     // 19,267,584
    const size_t n14 = (size_t)NB*14*14*DIMC;         //  4,816,896
    const size_t n7  = (size_t)NB*7*7*DIMC;           //  1,204,224
    float* region0 = ws;
    float* x7      = region0 + n28;      // also SE-partials scratch during phase A
    float* s0      = x7 + n7;
    float* s1      = s0 + NB*DIMC;
    float* pwpk_f  = s1 + NB*DIMC;       // 2 packed pw weights
    float* dyn     = pwpk_f + 36864;     // phase A: x14 ; phase B: packed weights
    size_t fixedf  = n28 + n7 + 2ull*NB*DIMC + 36864;
    if (ws_size < (fixedf + n14) * sizeof(float)) return;
    float* x14 = dyn;
    unsigned short* pwpk = (unsigned short*)pwpk_f;

    unsigned short* pk = (unsigned short*)dyn;
    const size_t PK_QKV0 = 0;                 // 576x192
    const size_t PK_QKV1 = PK_QKV0 + 576*192; // 384x192
    const size_t PK_PRJ0 = PK_QKV1 + 384*192;
    const size_t PK_PRJ1 = PK_PRJ0 + 192*192;
    const size_t PK_FC10 = PK_PRJ1 + 192*192;
    const size_t PK_FC11 = PK_FC10 + 768*192;
    const size_t PK_FC20 = PK_FC11 + 768*192;
    const size_t PK_FC21 = PK_FC20 + 192*768; // total 847872 ushorts < n14 floats

    // ---- pack pw weights (2 segments, one launch)
    {
        PackArgs a = {};
        a.src[0] = fe_pw[0]; a.dst[0] = pwpk;         a.K[0] = 192; a.tEnd[0] = 4608;
        a.src[1] = fe_pw[1]; a.dst[1] = pwpk + 36864; a.K[1] = 192; a.tEnd[1] = 9216;
        a.nseg = 2;
        pack_multi_kernel<<<(9216 + 255)/256, 256, 0, stream>>>(a);
    }

    // ---- Phase A: GlobalQueryGen: 28 -> 14 -> 7
    for (int fe = 0; fe < 2; ++fe){
        int H = fe ? 14 : 28;
        int HW = H * H;
        int M = NB * HW;
        const float* src = fe ? x14 : x;
        float* dst = fe ? x7 : x14;
        dw_gelu_kernel<<<NB*HW, DIMC, 0, stream>>>(src, fe_dw[fe], region0, H, H);
        se_reduce_kernel<<<NB*SEPARTS, DIMC, 0, stream>>>(region0, x7, HW);
        se_mlp_kernel<<<NB, DIMC, 0, stream>>>(x7, fe_se1[fe], fe_se2[fe], s1, HW);
        int ppw = pick_ppw(M);
        dim3 ga((M + 128*ppw - 1) / (128*ppw), 1);
        gemmW_kernel<<<ga, 256, 0, stream>>>(region0, pwpk + fe*36864, nullptr,
                                             src, region0, DIMC, M, ppw, s1, HW);
        maxpool_kernel<<<NB*(H/2)*(H/2), DIMC, 0, stream>>>(region0, dst, H, H);
    }

    // ---- pack remaining weights (8 segments, one launch; x14 dead now)
    {
        PackArgs a = {};
        const float* srcs[8] = {qkvw[0], qkvw[1], prjw[0], prjw[1],
                                fc1w[0], fc1w[1], fc2w[0], fc2w[1]};
        size_t offs[8] = {PK_QKV0, PK_QKV1, PK_PRJ0, PK_PRJ1,
                          PK_FC10, PK_FC11, PK_FC20, PK_FC21};
        int kk[8]  = {192, 192, 192, 192, 192, 192, 768, 768};
        int cnt[8] = {13824, 9216, 4608, 4608, 18432, 18432, 18432, 18432};
        int cum = 0;
        for (int i = 0; i < 8; ++i){
            a.src[i] = srcs[i]; a.dst[i] = pk + offs[i]; a.K[i] = kk[i];
            cum += cnt[i]; a.tEnd[i] = cum;
        }
        a.nseg = 8;
        pack_multi_kernel<<<(cum + 255)/256, 256, 0, stream>>>(a);
    }

    // ---- Phase B: two attention blocks (0=local, 1=global query)
    for (int blk = 0; blk < 2; ++blk){
        const float* xin = blk ? (const float*)out : x;
        ln_kernel<<<TOK28/4, 256, 0, stream>>>(xin, n1g[blk], n1b[blk], region0);
        int F = blk ? 384 : 576;
        attn_fused_kernel<<<NB*16, 512, 0, stream>>>(
            region0, pk + (blk ? PK_QKV1 : PK_QKV0), qkvb[blk],
            blk ? x7 : nullptr, rpb[blk], F);
        {
            int M = TOK28;
            int ppw = pick_ppw(M);
            dim3 gp((M + 128*ppw - 1) / (128*ppw), 1);
            gemmW_kernel<<<gp, 256, 0, stream>>>(region0,
                pk + (blk ? PK_PRJ1 : PK_PRJ0), prjb[blk], xin, out,
                DIMC, M, ppw, nullptr, 0);
        }
        ln_kernel<<<TOK28/4, 256, 0, stream>>>(out, n2g[blk], n2b[blk], region0);
        mlp_mfma_kernel<<<TOK28/64, 256, 0, stream>>>(region0,
            pk + (blk ? PK_FC11 : PK_FC10), fc1b[blk],
            pk + (blk ? PK_FC21 : PK_FC20), fc2b[blk], out);
    }
}

// Round 15
// 1117.773 us; speedup vs baseline: 1.5832x; 1.1283x over previous
//
#include <hip/hip_runtime.h>
#include <hip/hip_bf16.h>
#include <math.h>

#define NB     128
#define RESX   28
#define DIMC   192
#define NHEADS 6
#define WSZ    7
#define HD     32
#define NTOK   49
#define SCALE  0.17677669529663687f   // 32^-0.5
#define TOK28  (NB*RESX*RESX)         // 100352
#define QSTR   208                    // ushorts per q/k row
#define VSTR   80                     // ushorts per vt row
#define PSTR   80                     // ushorts per P row
#define HSTR   200                    // ushorts per h row (r7-verified)
#define SEPARTS 8

typedef short    bf16x8 __attribute__((ext_vector_type(8)));
typedef float    f32x4  __attribute__((ext_vector_type(4)));

__device__ __forceinline__ float gelu_f(float x){          // exact erf GELU (r7-verified)
    return 0.5f * x * (1.0f + erff(x * 0.70710678118654752f));
}
__device__ __forceinline__ unsigned short f2bf(float f){
    unsigned int u = __float_as_uint(f);
    u += 0x7fffu + ((u >> 16) & 1u);          // RNE
    return (unsigned short)(u >> 16);
}
__device__ __forceinline__ float bf2f(unsigned short u){
    return __uint_as_float(((unsigned int)u) << 16);
}
__device__ __forceinline__ bf16x8 pack8(float4 u, float4 v){
    bf16x8 r;
    r[0]=(short)f2bf(u.x); r[1]=(short)f2bf(u.y); r[2]=(short)f2bf(u.z); r[3]=(short)f2bf(u.w);
    r[4]=(short)f2bf(v.x); r[5]=(short)f2bf(v.y); r[6]=(short)f2bf(v.z); r[7]=(short)f2bf(v.w);
    return r;
}

// ---------------- LayerNorm: one wave per token (4 tokens / 256-thread block)
__global__ __launch_bounds__(256) void ln_kernel(const float* __restrict__ x,
        const float* __restrict__ g, const float* __restrict__ be,
        float* __restrict__ out)
{
    int wid = threadIdx.x >> 6, lane = threadIdx.x & 63;
    size_t tok = (size_t)blockIdx.x * 4 + wid;
    const float* xr = x + tok * DIMC;
    float v0 = xr[lane], v1 = xr[lane + 64], v2 = xr[lane + 128];
    float s  = v0 + v1 + v2;
    float sq = v0*v0 + v1*v1 + v2*v2;
    #pragma unroll
    for (int o = 32; o > 0; o >>= 1){ s += __shfl_xor(s, o); sq += __shfl_xor(sq, o); }
    float mean = s * (1.0f/DIMC);
    float var  = sq * (1.0f/DIMC) - mean*mean;
    float rstd = rsqrtf(var + 1e-5f);
    float* orow = out + tok * DIMC;
    orow[lane]     = (v0-mean)*rstd*g[lane]     + be[lane];
    orow[lane+64]  = (v1-mean)*rstd*g[lane+64]  + be[lane+64];
    orow[lane+128] = (v2-mean)*rstd*g[lane+128] + be[lane+128];
}

// ---------------- depthwise 3x3 (NHWC) + exact GELU, vectorized:
// 4 pixels/block, 192 threads (pix = t/48, c4 = t%48), float4 taps, weights in LDS
__global__ __launch_bounds__(192) void dw_gelu_kernel(const float* __restrict__ x,
        const float* __restrict__ dw, float* __restrict__ y, int H, int W)
{
    __shared__ float wl[DIMC*9];
    int tx = threadIdx.x;
    #pragma unroll
    for (int q = 0; q < 9; ++q) wl[tx*9 + q] = dw[tx*9 + q];
    __syncthreads();
    int pix = tx / 48, c4 = tx - (tx/48)*48;
    int p = blockIdx.x*4 + pix;
    int w = p % W; int h = (p / W) % H; int b = p / (W*H);
    float wk[9][4];
    #pragma unroll
    for (int q = 0; q < 9; ++q){
        #pragma unroll
        for (int cc = 0; cc < 4; ++cc) wk[q][cc] = wl[(c4*4 + cc)*9 + q];
    }
    const float* base = x + (size_t)b*H*W*DIMC + c4*4;
    float4 acc = make_float4(0.f, 0.f, 0.f, 0.f);
    #pragma unroll
    for (int kh = 0; kh < 3; ++kh){
        int hh = h + kh - 1; if (hh < 0 || hh >= H) continue;
        #pragma unroll
        for (int kw = 0; kw < 3; ++kw){
            int ww = w + kw - 1; if (ww < 0 || ww >= W) continue;
            float4 v = *(const float4*)(base + ((size_t)hh*W + ww)*DIMC);
            int q = kh*3 + kw;
            acc.x += v.x*wk[q][0]; acc.y += v.y*wk[q][1];
            acc.z += v.z*wk[q][2]; acc.w += v.w*wk[q][3];
        }
    }
    float4 o;
    o.x = gelu_f(acc.x); o.y = gelu_f(acc.y);
    o.z = gelu_f(acc.z); o.w = gelu_f(acc.w);
    *(float4*)(y + (size_t)p*DIMC + c4*4) = o;
}

// ---------------- SE: partial average pool (SEPARTS blocks per image)
__global__ void se_reduce_kernel(const float* __restrict__ y, float* __restrict__ part,
                                 int HW)
{
    int blk = blockIdx.x;                 // b*SEPARTS + i
    int b = blk / SEPARTS, i = blk - b*SEPARTS;
    int c = threadIdx.x;
    int chunk = (HW + SEPARTS - 1) / SEPARTS;
    int p0 = i*chunk, p1 = p0 + chunk;
    if (p1 > HW) p1 = HW;
    const float* base = y + (size_t)b*HW*DIMC + c;
    float acc = 0.f;
    for (int p = p0; p < p1; ++p) acc += base[(size_t)p*DIMC];
    part[(size_t)blk*DIMC + c] = acc;
}

// ---------------- SE: merge partials -> 192 -> gelu(48) -> sigmoid(192)
__global__ void se_mlp_kernel(const float* __restrict__ part, const float* __restrict__ w1,
                              const float* __restrict__ w2, float* __restrict__ s, int HW)
{
    __shared__ float sl[DIMC];
    __shared__ float mid[48];
    int b = blockIdx.x; int t = threadIdx.x;
    float acc0 = 0.f;
    #pragma unroll
    for (int i = 0; i < SEPARTS; ++i)
        acc0 += part[((size_t)b*SEPARTS + i)*DIMC + t];
    sl[t] = acc0 / (float)HW;
    __syncthreads();
    if (t < 48){
        float acc = 0.f;
        for (int c = 0; c < DIMC; ++c) acc += sl[c] * w1[t*DIMC + c];
        mid[t] = gelu_f(acc);
    }
    __syncthreads();
    float acc = 0.f;
    #pragma unroll 8
    for (int j = 0; j < 48; ++j) acc += mid[j] * w2[t*48 + j];
    s[b*DIMC + t] = 1.0f / (1.0f + expf(-acc));
}

// ---------------- maxpool 3x3 stride 2 pad 1 (NHWC), vectorized 4 pixels/block
__global__ __launch_bounds__(192) void maxpool_kernel(const float* __restrict__ x,
        float* __restrict__ out, int H, int W)
{
    int H2 = H >> 1, W2 = W >> 1;
    int tx = threadIdx.x;
    int pix = tx / 48, c4 = tx - (tx/48)*48;
    int p = blockIdx.x*4 + pix;
    if (p >= NB*H2*W2) return;
    int w2 = p % W2; int h2 = (p / W2) % H2; int b = p / (W2*H2);
    const float* base = x + (size_t)b*H*W*DIMC + c4*4;
    float4 m = make_float4(-INFINITY, -INFINITY, -INFINITY, -INFINITY);
    #pragma unroll
    for (int dh = -1; dh <= 1; ++dh){
        int h = 2*h2 + dh; if (h < 0 || h >= H) continue;
        #pragma unroll
        for (int dw = -1; dw <= 1; ++dw){
            int w = 2*w2 + dw; if (w < 0 || w >= W) continue;
            float4 v = *(const float4*)(base + ((size_t)h*W + w)*DIMC);
            m.x = fmaxf(m.x, v.x); m.y = fmaxf(m.y, v.y);
            m.z = fmaxf(m.z, v.z); m.w = fmaxf(m.w, v.w);
        }
    }
    *(float4*)(out + (size_t)p*DIMC + c4*4) = m;
}

// ---------------- merged weight pack: up to 8 segments in one launch
struct PackArgs {
    const float* src[8];
    unsigned short* dst[8];
    int K[8];
    int tEnd[8];
    int nseg;
};
__global__ __launch_bounds__(256) void pack_multi_kernel(PackArgs a)
{
    int t = blockIdx.x*256 + threadIdx.x;
    int seg = 0;
    while (seg < a.nseg && t >= a.tEnd[seg]) ++seg;
    if (seg >= a.nseg) return;
    int t0 = seg ? a.tEnd[seg-1] : 0;
    int tl = t - t0;
    int lane = tl & 63, frag = tl >> 6;
    int K = a.K[seg], ks = K >> 5;
    int j = frag / ks, s = frag - j*ks;
    const float* wr = a.src[seg] + (size_t)(j*16 + (lane & 15))*K + s*32 + ((lane>>4)<<3);
    bf16x8 r = pack8(*(const float4*)wr, *(const float4*)(wr + 4));
    *((bf16x8*)(a.dst[seg] + (size_t)tl*8)) = r;
}

// ---------------- weight-stationary MFMA GEMM (K=192, N=192-chunked in LDS)
__global__ __launch_bounds__(256) void gemmW_kernel(
    const float* __restrict__ in, const unsigned short* __restrict__ Wp,
    const float* __restrict__ bias, const float* __restrict__ res,
    float* __restrict__ out, int N, int M, int ppw,
    const float* __restrict__ sv, int HW)
{
    __shared__ __align__(16) unsigned short wlds[72*512];  // 73728 B
    __shared__ __align__(16) float sbias[192];
    int tid = threadIdx.x;
    int l = tid & 63, w = tid >> 6, c = l & 15, g = l >> 4;
    int nc = blockIdx.y;
    const bf16x8* wsrc = (const bf16x8*)(Wp + (size_t)nc*36864);
    bf16x8* wdst = (bf16x8*)wlds;
    #pragma unroll 2
    for (int i = tid; i < 4608; i += 256) wdst[i] = wsrc[i];
    if (tid < 48){
        float4 bb = bias ? ((const float4*)(bias + nc*192))[tid]
                         : make_float4(0.f,0.f,0.f,0.f);
        ((float4*)sbias)[tid] = bb;
    }
    __syncthreads();
    size_t mbase = (size_t)blockIdx.x*(128*ppw) + (size_t)w*(32*ppw);
    for (int p = 0; p < ppw; ++p){
        size_t m0 = mbase + (size_t)p*32;
        if ((long)m0 >= M) break;
        bool st1 = (long)(m0 + 16) < M;
        const float* ar0 = in + (m0 + c)*DIMC;
        const float* ar1 = ar0 + 16*DIMC;
        bf16x8 b0[6], b1[6];
        #pragma unroll
        for (int s = 0; s < 6; ++s){
            int k0 = s*32 + g*8;
            float4 u0 = *(const float4*)(ar0 + k0), v0 = *(const float4*)(ar0 + k0 + 4);
            float4 u1 = *(const float4*)(ar1 + k0), v1 = *(const float4*)(ar1 + k0 + 4);
            if (sv){
                int bi0 = (int)((m0 + c)/HW), bi1 = (int)((m0 + 16 + c)/HW);
                float4 a0 = *(const float4*)(sv + (size_t)bi0*DIMC + k0);
                float4 a1 = *(const float4*)(sv + (size_t)bi0*DIMC + k0 + 4);
                float4 d0 = *(const float4*)(sv + (size_t)bi1*DIMC + k0);
                float4 d1 = *(const float4*)(sv + (size_t)bi1*DIMC + k0 + 4);
                u0.x*=a0.x; u0.y*=a0.y; u0.z*=a0.z; u0.w*=a0.w;
                v0.x*=a1.x; v0.y*=a1.y; v0.z*=a1.z; v0.w*=a1.w;
                u1.x*=d0.x; u1.y*=d0.y; u1.z*=d0.z; u1.w*=d0.w;
                v1.x*=d1.x; v1.y*=d1.y; v1.z*=d1.z; v1.w*=d1.w;
            }
            b0[s] = pack8(u0, v0);
            b1[s] = pack8(u1, v1);
        }
        #pragma unroll 2
        for (int j = 0; j < 12; ++j){
            float4 bb = *(const float4*)(sbias + j*16 + g*4);
            f32x4 a0 = {bb.x, bb.y, bb.z, bb.w};
            f32x4 a1 = a0;
            const bf16x8* wf = (const bf16x8*)wlds + (size_t)j*6*64 + l;
            #pragma unroll
            for (int s = 0; s < 6; ++s){
                bf16x8 wfr = wf[s*64];
                a0 = __builtin_amdgcn_mfma_f32_16x16x32_bf16(wfr, b0[s], a0, 0, 0, 0);
                a1 = __builtin_amdgcn_mfma_f32_16x16x32_bf16(wfr, b1[s], a1, 0, 0, 0);
            }
            int ncol = nc*192 + j*16 + g*4;
            size_t o0 = (m0 + c)*(size_t)N + ncol;
            size_t o1 = o0 + (size_t)16*N;
            float4 r0 = res ? *(const float4*)(res + o0) : make_float4(0.f,0.f,0.f,0.f);
            *(float4*)(out + o0) = make_float4(a0[0]+r0.x, a0[1]+r0.y, a0[2]+r0.z, a0[3]+r0.w);
            if (st1){
                float4 r1 = res ? *(const float4*)(res + o1) : make_float4(0.f,0.f,0.f,0.f);
                *(float4*)(out + o1) = make_float4(a1[0]+r1.x, a1[1]+r1.y, a1[2]+r1.z, a1[3]+r1.w);
            }
        }
    }
}

// ---------------- fused MFMA MLP v3 + double-buffered h (r14-verified)
__global__ __launch_bounds__(256, 2) void mlp_mfma_kernel(
    const float* __restrict__ xln,
    const unsigned short* __restrict__ W1p, const float* __restrict__ b1,
    const unsigned short* __restrict__ W2p, const float* __restrict__ b2,
    float* __restrict__ xout)
{
    __shared__ __align__(16) unsigned short h[2][64*HSTR];   // 51200 B
    int l = threadIdx.x & 63, w = threadIdx.x >> 6;
    int c = l & 15, g = l >> 4;
    size_t m0 = (size_t)blockIdx.x*64;
    bf16x8 bx[4][6];
    #pragma unroll
    for (int mt = 0; mt < 4; ++mt){
        const float* ar = xln + (m0 + mt*16 + c)*DIMC;
        #pragma unroll
        for (int s = 0; s < 6; ++s){
            int k0 = s*32 + g*8;
            bx[mt][s] = pack8(*(const float4*)(ar + k0), *(const float4*)(ar + k0 + 4));
        }
    }
    f32x4 acc[4][3];
    #pragma unroll
    for (int jj = 0; jj < 3; ++jj){
        float4 b4 = *(const float4*)(b2 + (3*w + jj)*16 + g*4);
        f32x4 v = {b4.x, b4.y, b4.z, b4.w};
        #pragma unroll
        for (int mt = 0; mt < 4; ++mt) acc[mt][jj] = v;
    }
    for (int ch = 0; ch < 4; ++ch){
        unsigned short* hb = &h[ch & 1][0];
        #pragma unroll
        for (int jj = 0; jj < 3; ++jj){
            int j = ch*12 + 3*w + jj;
            float4 b40 = *(const float4*)(b1 + j*16 + g*4);
            f32x4 a0 = {b40.x, b40.y, b40.z, b40.w};
            f32x4 a1 = a0, a2 = a0, a3 = a0;
            const bf16x8* wp = (const bf16x8*)(W1p + ((size_t)(j*6)*64 + l)*8);
            #pragma unroll
            for (int s = 0; s < 6; ++s){
                bf16x8 wfr = wp[s*64];
                a0 = __builtin_amdgcn_mfma_f32_16x16x32_bf16(wfr, bx[0][s], a0, 0, 0, 0);
                a1 = __builtin_amdgcn_mfma_f32_16x16x32_bf16(wfr, bx[1][s], a1, 0, 0, 0);
                a2 = __builtin_amdgcn_mfma_f32_16x16x32_bf16(wfr, bx[2][s], a2, 0, 0, 0);
                a3 = __builtin_amdgcn_mfma_f32_16x16x32_bf16(wfr, bx[3][s], a3, 0, 0, 0);
            }
            int fb = (3*w + jj)*16 + g*4;
            ushort4 u;
            u.x=f2bf(gelu_f(a0[0])); u.y=f2bf(gelu_f(a0[1]));
            u.z=f2bf(gelu_f(a0[2])); u.w=f2bf(gelu_f(a0[3]));
            *(ushort4*)(hb + (0*16 + c)*HSTR + fb) = u;
            u.x=f2bf(gelu_f(a1[0])); u.y=f2bf(gelu_f(a1[1]));
            u.z=f2bf(gelu_f(a1[2])); u.w=f2bf(gelu_f(a1[3]));
            *(ushort4*)(hb + (1*16 + c)*HSTR + fb) = u;
            u.x=f2bf(gelu_f(a2[0])); u.y=f2bf(gelu_f(a2[1]));
            u.z=f2bf(gelu_f(a2[2])); u.w=f2bf(gelu_f(a2[3]));
            *(ushort4*)(hb + (2*16 + c)*HSTR + fb) = u;
            u.x=f2bf(gelu_f(a3[0])); u.y=f2bf(gelu_f(a3[1]));
            u.z=f2bf(gelu_f(a3[2])); u.w=f2bf(gelu_f(a3[3]));
            *(ushort4*)(hb + (3*16 + c)*HSTR + fb) = u;
        }
        __syncthreads();
        #pragma unroll
        for (int s = 0; s < 6; ++s){
            bf16x8 hf[4];
            #pragma unroll
            for (int mt = 0; mt < 4; ++mt)
                hf[mt] = *(const bf16x8*)(hb + (mt*16 + c)*HSTR + s*32 + g*8);
            #pragma unroll
            for (int jj = 0; jj < 3; ++jj){
                int j = 3*w + jj;
                bf16x8 wf = *(const bf16x8*)(W2p + ((size_t)(j*24 + ch*6 + s)*64 + l)*8);
                #pragma unroll
                for (int mt = 0; mt < 4; ++mt)
                    acc[mt][jj] = __builtin_amdgcn_mfma_f32_16x16x32_bf16(wf, hf[mt], acc[mt][jj], 0, 0, 0);
            }
        }
    }
    #pragma unroll
    for (int mt = 0; mt < 4; ++mt){
        #pragma unroll
        for (int jj = 0; jj < 3; ++jj){
            size_t o = (m0 + mt*16 + c)*DIMC + (3*w + jj)*16 + g*4;
            float4 r = *(const float4*)(xout + o);
            *(float4*)(xout + o) = make_float4(acc[mt][jj][0]+r.x, acc[mt][jj][1]+r.y,
                                               acc[mt][jj][2]+r.z, acc[mt][jj][3]+r.w);
        }
    }
}

// ---------------- fused qkv + window attention, all-MFMA (r14-verified)
__global__ __launch_bounds__(512, 2) void attn_fused_kernel(
    float* __restrict__ xio, const unsigned short* __restrict__ Wp,
    const float* __restrict__ bias, const float* __restrict__ qg,
    const float* __restrict__ rpb, int F)
{
    __shared__ __align__(16) unsigned short q_lds[64*QSTR];  // 26624 B
    __shared__ __align__(16) unsigned short k_lds[64*QSTR];  // 26624 B
    __shared__ __align__(16) unsigned short vt[192*VSTR];    // 30720 B
    __shared__ __align__(16) unsigned short pp[8*16*PSTR];   // 20480 B
    __shared__ float sinv_l[8*16];
    __shared__ float rpb_l[NHEADS*169];
    int tid = threadIdx.x;
    int w8 = tid >> 6;
    int l = tid & 63, c = l & 15, g = l >> 4;
    int blk = blockIdx.x;
    int b = blk >> 4, win = blk & 15;
    int wr = win >> 2, wc = win & 3;
    bool isglobal = (F == 384);

    for (int i = tid; i < 15*QSTR; i += 512){
        q_lds[49*QSTR + i] = 0; k_lds[49*QSTR + i] = 0;
    }
    for (int i = tid; i < 192*15; i += 512){
        int d = i / 15, t = 49 + (i - d*15);
        vt[d*VSTR + t] = 0;
    }
    for (int i = tid; i < NHEADS*169; i += 512){
        int hd = i / 169, r = i - hd*169;
        rpb_l[i] = rpb[r*NHEADS + hd];
    }

    // ---- phase 1: qkv projection via MFMA
    {
        bf16x8 bx[4][6];
        #pragma unroll
        for (int mt = 0; mt < 4; ++mt){
            int t = mt*16 + c;
            if (t < NTOK){
                int hh = wr*WSZ + t/WSZ, ww = wc*WSZ + t - (t/WSZ)*WSZ;
                const float* ar = xio + (((size_t)b*RESX + hh)*RESX + ww)*DIMC;
                #pragma unroll
                for (int s = 0; s < 6; ++s){
                    int k0 = s*32 + g*8;
                    bx[mt][s] = pack8(*(const float4*)(ar + k0), *(const float4*)(ar + k0 + 4));
                }
            } else {
                bf16x8 z = {0,0,0,0,0,0,0,0};
                #pragma unroll
                for (int s = 0; s < 6; ++s) bx[mt][s] = z;
            }
        }
        int ntile = F >> 4;    // 36 local / 24 global
        for (int jn = w8; jn < ntile; jn += 8){
            float4 bb4 = *(const float4*)(bias + jn*16 + g*4);
            f32x4 a0 = {bb4.x, bb4.y, bb4.z, bb4.w};
            f32x4 a1 = a0, a2 = a0, a3 = a0;
            const bf16x8* wp = (const bf16x8*)(Wp + ((size_t)(jn*6)*64 + l)*8);
            #pragma unroll
            for (int s = 0; s < 6; ++s){
                bf16x8 wfr = wp[s*64];
                a0 = __builtin_amdgcn_mfma_f32_16x16x32_bf16(wfr, bx[0][s], a0, 0, 0, 0);
                a1 = __builtin_amdgcn_mfma_f32_16x16x32_bf16(wfr, bx[1][s], a1, 0, 0, 0);
                a2 = __builtin_amdgcn_mfma_f32_16x16x32_bf16(wfr, bx[2][s], a2, 0, 0, 0);
                a3 = __builtin_amdgcn_mfma_f32_16x16x32_bf16(wfr, bx[3][s], a3, 0, 0, 0);
            }
            int sect = jn / 12 + (isglobal ? 1 : 0);   // 0=q,1=k,2=v
            int frel = (jn - (jn/12)*12)*16 + g*4;
            f32x4 av[4] = {a0, a1, a2, a3};
            #pragma unroll
            for (int mt = 0; mt < 4; ++mt){
                int t = mt*16 + c;
                if (t >= NTOK) continue;
                f32x4 a = av[mt];
                if (sect == 0){
                    ushort4 u;
                    u.x=f2bf(a[0]*SCALE); u.y=f2bf(a[1]*SCALE);
                    u.z=f2bf(a[2]*SCALE); u.w=f2bf(a[3]*SCALE);
                    *(ushort4*)(q_lds + t*QSTR + frel) = u;
                } else if (sect == 1){
                    ushort4 u;
                    u.x=f2bf(a[0]); u.y=f2bf(a[1]); u.z=f2bf(a[2]); u.w=f2bf(a[3]);
                    *(ushort4*)(k_lds + t*QSTR + frel) = u;
                } else {
                    vt[(frel+0)*VSTR + t] = f2bf(a[0]);
                    vt[(frel+1)*VSTR + t] = f2bf(a[1]);
                    vt[(frel+2)*VSTR + t] = f2bf(a[2]);
                    vt[(frel+3)*VSTR + t] = f2bf(a[3]);
                }
            }
        }
        if (isglobal){
            for (int i = tid; i < NTOK*48; i += 512){
                int t = i / 48, f4 = i - (i/48)*48;
                float4 qv = *(const float4*)(qg + ((size_t)b*NTOK + t)*DIMC + f4*4);
                ushort4 u;
                u.x=f2bf(qv.x*SCALE); u.y=f2bf(qv.y*SCALE);
                u.z=f2bf(qv.z*SCALE); u.w=f2bf(qv.w*SCALE);
                *(ushort4*)(q_lds + t*QSTR + f4*4) = u;
            }
        }
    }
    __syncthreads();

    // ---- 24 attention units, 3 per wave (barrier-free role-diverse phase)
    for (int uu = 0; uu < 3; ++uu){
        int unit = w8*3 + uu;
        int ti = unit / 6, hd = unit - (unit/6)*6;
        bf16x8 qa = *(const bf16x8*)(q_lds + (16*ti + c)*QSTR + hd*HD + g*8);
        f32x4 S[4];
        {
            const f32x4 z = {0.f, 0.f, 0.f, 0.f};
            __builtin_amdgcn_s_setprio(1);
            #pragma unroll
            for (int tj = 0; tj < 4; ++tj){
                bf16x8 kb = *(const bf16x8*)(k_lds + (16*tj + c)*QSTR + hd*HD + g*8);
                S[tj] = __builtin_amdgcn_mfma_f32_16x16x32_bf16(qa, kb, z, 0, 0, 0);
            }
            __builtin_amdgcn_s_setprio(0);
        }
        float tot[4] = {0.f, 0.f, 0.f, 0.f};
        unsigned short pu[4][4];
        int ibase = 16*ti + g*4;
        #pragma unroll
        for (int tj = 0; tj < 4; ++tj){
            int j = 16*tj + c;
            bool jok = (j < NTOK);
            int jc = jok ? j : 0;
            int rj = jc / 7, cj = jc - rj*7;
            #pragma unroll
            for (int r = 0; r < 4; ++r){
                int i = ibase + r;
                int ic = (i < NTOK) ? i : 0;
                int ri = ic / 7, ci = ic - ri*7;
                unsigned short u16 = 0;
                if (jok){
                    float bv = rpb_l[hd*169 + (ri - rj + 6)*13 + (ci - cj + 6)];
                    u16 = f2bf(__expf(S[tj][r] + bv));
                }
                pu[tj][r] = u16;
                tot[r] += bf2f(u16);
            }
        }
        #pragma unroll
        for (int r = 0; r < 4; ++r){
            float t0 = tot[r];
            t0 += __shfl_xor(t0, 1); t0 += __shfl_xor(t0, 2);
            t0 += __shfl_xor(t0, 4); t0 += __shfl_xor(t0, 8);
            tot[r] = t0;
        }
        if (c == 0){
            #pragma unroll
            for (int r = 0; r < 4; ++r)
                sinv_l[w8*16 + g*4 + r] = 1.0f / tot[r];
        }
        #pragma unroll
        for (int tj = 0; tj < 4; ++tj){
            #pragma unroll
            for (int r = 0; r < 4; ++r)
                pp[(w8*16 + g*4 + r)*PSTR + 16*tj + c] = pu[tj][r];
        }
        bf16x8 pb0 = *(const bf16x8*)(pp + (w8*16 + c)*PSTR + g*8);
        bf16x8 pb1 = *(const bf16x8*)(pp + (w8*16 + c)*PSTR + 32 + g*8);
        float si = sinv_l[w8*16 + c];
        int t = 16*ti + c;
        #pragma unroll
        for (int dm = 0; dm < 2; ++dm){
            int vrow = hd*HD + dm*16 + c;
            bf16x8 va0 = *(const bf16x8*)(vt + vrow*VSTR + g*8);
            bf16x8 va1 = *(const bf16x8*)(vt + vrow*VSTR + 32 + g*8);
            const f32x4 z = {0.f, 0.f, 0.f, 0.f};
            __builtin_amdgcn_s_setprio(1);
            f32x4 o = __builtin_amdgcn_mfma_f32_16x16x32_bf16(va0, pb0, z, 0, 0, 0);
            o = __builtin_amdgcn_mfma_f32_16x16x32_bf16(va1, pb1, o, 0, 0, 0);
            __builtin_amdgcn_s_setprio(0);
            if (t < NTOK){
                int hh = wr*WSZ + t/WSZ, ww = wc*WSZ + t - (t/WSZ)*WSZ;
                float4 ov = make_float4(o[0]*si, o[1]*si, o[2]*si, o[3]*si);
                *(float4*)(xio + (((size_t)b*RESX + hh)*RESX + ww)*DIMC
                           + hd*HD + dm*16 + g*4) = ov;
            }
        }
    }
}

static inline int pick_ppw(int M){
    int ppw = M / 65536;                 // target >= ~512 blocks (2 per CU)
    if (ppw < 1) ppw = 1;
    if (ppw > 8) ppw = 8;
    return ppw;
}

extern "C" void kernel_launch(void* const* d_in, const int* in_sizes, int n_in,
                              void* d_out, int out_size, void* d_ws, size_t ws_size,
                              hipStream_t stream)
{
    (void)in_sizes; (void)n_in; (void)out_size;
    const float* x = (const float*)d_in[0];
    const float* fe_dw[2]  = {(const float*)d_in[1], (const float*)d_in[5]};
    const float* fe_se1[2] = {(const float*)d_in[2], (const float*)d_in[6]};
    const float* fe_se2[2] = {(const float*)d_in[3], (const float*)d_in[7]};
    const float* fe_pw[2]  = {(const float*)d_in[4], (const float*)d_in[8]};
    const float* n1g[2]  = {(const float*)d_in[9],  (const float*)d_in[22]};
    const float* n1b[2]  = {(const float*)d_in[10], (const float*)d_in[23]};
    const float* qkvw[2] = {(const float*)d_in[11], (const float*)d_in[24]};
    const float* qkvb[2] = {(const float*)d_in[12], (const float*)d_in[25]};
    const float* rpb[2]  = {(const float*)d_in[13], (const float*)d_in[26]};
    const float* prjw[2] = {(const float*)d_in[14], (const float*)d_in[27]};
    const float* prjb[2] = {(const float*)d_in[15], (const float*)d_in[28]};
    const float* n2g[2]  = {(const float*)d_in[16], (const float*)d_in[29]};
    const float* n2b[2]  = {(const float*)d_in[17], (const float*)d_in[30]};
    const float* fc1w[2] = {(const float*)d_in[18], (const float*)d_in[31]};
    const float* fc1b[2] = {(const float*)d_in[19], (const float*)d_in[32]};
    const float* fc2w[2] = {(const float*)d_in[20], (const float*)d_in[33]};
    const float* fc2b[2] = {(const float*)d_in[21], (const float*)d_in[34]};

    float* out = (float*)d_out;
    float* ws = (float*)d_ws;
    const size_t n28 = (size_t)NB*RESX*RESX*DIMC;     // 19,267,584
    const size_t n14 = (size_t)NB*14*14*DIMC;         //  4,816,896
    const size_t n7  = (size_t)NB*7*7*DIMC;           //  1,204,224
    float* region0 = ws;
    float* x7      = region0 + n28;      // also SE-partials scratch during phase A
    float* s0      = x7 + n7;
    float* s1      = s0 + NB*DIMC;
    float* pwpk_f  = s1 + NB*DIMC;       // 2 packed pw weights
    float* dyn     = pwpk_f + 36864;     // phase A: x14 ; phase B: packed weights
    size_t fixedf  = n28 + n7 + 2ull*NB*DIMC + 36864;
    if (ws_size < (fixedf + n14) * sizeof(float)) return;
    float* x14 = dyn;
    unsigned short* pwpk = (unsigned short*)pwpk_f;

    unsigned short* pk = (unsigned short*)dyn;
    const size_t PK_QKV0 = 0;                 // 576x192
    const size_t PK_QKV1 = PK_QKV0 + 576*192; // 384x192
    const size_t PK_PRJ0 = PK_QKV1 + 384*192;
    const size_t PK_PRJ1 = PK_PRJ0 + 192*192;
    const size_t PK_FC10 = PK_PRJ1 + 192*192;
    const size_t PK_FC11 = PK_FC10 + 768*192;
    const size_t PK_FC20 = PK_FC11 + 768*192;
    const size_t PK_FC21 = PK_FC20 + 192*768; // total 847872 ushorts < n14 floats

    // ---- pack pw weights (2 segments, one launch)
    {
        PackArgs a = {};
        a.src[0] = fe_pw[0]; a.dst[0] = pwpk;         a.K[0] = 192; a.tEnd[0] = 4608;
        a.src[1] = fe_pw[1]; a.dst[1] = pwpk + 36864; a.K[1] = 192; a.tEnd[1] = 9216;
        a.nseg = 2;
        pack_multi_kernel<<<(9216 + 255)/256, 256, 0, stream>>>(a);
    }

    // ---- Phase A: GlobalQueryGen: 28 -> 14 -> 7
    for (int fe = 0; fe < 2; ++fe){
        int H = fe ? 14 : 28;
        int HW = H * H;
        int M = NB * HW;
        const float* src = fe ? x14 : x;
        float* dst = fe ? x7 : x14;
        dw_gelu_kernel<<<NB*HW/4, 192, 0, stream>>>(src, fe_dw[fe], region0, H, H);
        se_reduce_kernel<<<NB*SEPARTS, DIMC, 0, stream>>>(region0, x7, HW);
        se_mlp_kernel<<<NB, DIMC, 0, stream>>>(x7, fe_se1[fe], fe_se2[fe], s1, HW);
        int ppw = pick_ppw(M);
        dim3 ga((M + 128*ppw - 1) / (128*ppw), 1);
        gemmW_kernel<<<ga, 256, 0, stream>>>(region0, pwpk + fe*36864, nullptr,
                                             src, region0, DIMC, M, ppw, s1, HW);
        int npool = NB*(H/2)*(H/2);
        maxpool_kernel<<<(npool + 3)/4, 192, 0, stream>>>(region0, dst, H, H);
    }

    // ---- pack remaining weights (8 segments, one launch; x14 dead now)
    {
        PackArgs a = {};
        const float* srcs[8] = {qkvw[0], qkvw[1], prjw[0], prjw[1],
                                fc1w[0], fc1w[1], fc2w[0], fc2w[1]};
        size_t offs[8] = {PK_QKV0, PK_QKV1, PK_PRJ0, PK_PRJ1,
                          PK_FC10, PK_FC11, PK_FC20, PK_FC21};
        int kk[8]  = {192, 192, 192, 192, 192, 192, 768, 768};
        int cnt[8] = {13824, 9216, 4608, 4608, 18432, 18432, 18432, 18432};
        int cum = 0;
        for (int i = 0; i < 8; ++i){
            a.src[i] = srcs[i]; a.dst[i] = pk + offs[i]; a.K[i] = kk[i];
            cum += cnt[i]; a.tEnd[i] = cum;
        }
        a.nseg = 8;
        pack_multi_kernel<<<(cum + 255)/256, 256, 0, stream>>>(a);
    }

    // ---- Phase B: two attention blocks (0=local, 1=global query)
    for (int blk = 0; blk < 2; ++blk){
        const float* xin = blk ? (const float*)out : x;
        ln_kernel<<<TOK28/4, 256, 0, stream>>>(xin, n1g[blk], n1b[blk], region0);
        int F = blk ? 384 : 576;
        attn_fused_kernel<<<NB*16, 512, 0, stream>>>(
            region0, pk + (blk ? PK_QKV1 : PK_QKV0), qkvb[blk],
            blk ? x7 : nullptr, rpb[blk], F);
        {
            int M = TOK28;
            int ppw = pick_ppw(M);
            dim3 gp((M + 128*ppw - 1) / (128*ppw), 1);
            gemmW_kernel<<<gp, 256, 0, stream>>>(region0,
                pk + (blk ? PK_PRJ1 : PK_PRJ0), prjb[blk], xin, out,
                DIMC, M, ppw, nullptr, 0);
        }
        ln_kernel<<<TOK28/4, 256, 0, stream>>>(out, n2g[blk], n2b[blk], region0);
        mlp_mfma_kernel<<<TOK28/64, 256, 0, stream>>>(region0,
            pk + (blk ? PK_FC11 : PK_FC10), fc1b[blk],
            pk + (blk ? PK_FC21 : PK_FC20), fc2b[blk], out);
    }
}